// Round 6
// baseline (444.052 us; speedup 1.0000x reference)
//
#include <hip/hip_runtime.h>

// ---------------- problem constants ----------------
#define HID   2048
#define NHEAD 16
#define HD    128
#define SEQ   2048
#define BATCH 2
#define MROWS (BATCH*SEQ)        // 4096
#define NQKV  (3*HID)            // 6144
#define INV_NORM 0.08838834764831845f
#define LOG2E    1.4426950408889634f
#define SCALE_L2 (INV_NORM*LOG2E)

typedef __attribute__((ext_vector_type(8)))  __bf16 bf16x8;
typedef __attribute__((ext_vector_type(4)))  float  f32x4;
typedef __attribute__((ext_vector_type(16))) float  f32x16;

typedef __attribute__((address_space(1))) void GV;
typedef __attribute__((address_space(3))) void LV;

__device__ __forceinline__ void async16(const void* g, void* l) {
  __builtin_amdgcn_global_load_lds((const GV*)g, (LV*)l, 16, 0, 0);
}

__device__ __forceinline__ unsigned short f2bf(float f) {
  unsigned u = __builtin_bit_cast(unsigned, f);
  u += 0x7FFFu + ((u >> 16) & 1u);       // RNE
  return (unsigned short)(u >> 16);
}

__device__ __forceinline__ unsigned pkbf(float a, float b) {
#if __has_builtin(__builtin_amdgcn_cvt_pk_bf16_f32)
  typedef __attribute__((ext_vector_type(2))) __bf16 bf16x2;
  bf16x2 r = __builtin_amdgcn_cvt_pk_bf16_f32(a, b);
  return __builtin_bit_cast(unsigned, r);
#else
  return (unsigned)f2bf(a) | ((unsigned)f2bf(b) << 16);
#endif
}

__device__ __forceinline__ void mfma16(f32x4& c, bf16x8 a, bf16x8 b) {
  c = __builtin_amdgcn_mfma_f32_16x16x32_bf16(a, b, c, 0, 0, 0);
}

// LDS fragment read with chunk-XOR swizzle (BK=64 -> 8 chunks of 16B per row)
__device__ __forceinline__ bf16x8 frag(const unsigned short* buf, int row, int chunk) {
  return *(const bf16x8*)(buf + ((row * 8 + (chunk ^ (row & 7))) << 3));
}

// ---------------- fp32 -> bf16 casts ----------------
__global__ __launch_bounds__(256) void cvt_kernel(const float* __restrict__ src,
                                                  unsigned short* __restrict__ dst, int n) {
  int i = (blockIdx.x * 256 + threadIdx.x) * 4;
  if (i >= n) return;
  float4 v = *(const float4*)(src + i);
  ushort4 o;
  o.x = f2bf(v.x); o.y = f2bf(v.y); o.z = f2bf(v.z); o.w = f2bf(v.w);
  *(ushort4*)(dst + i) = o;
}

__global__ __launch_bounds__(256) void cvtw_kernel(const float* __restrict__ W0,
                                                   const float* __restrict__ W1,
                                                   const float* __restrict__ W2,
                                                   const float* __restrict__ W3,
                                                   unsigned short* __restrict__ dst) {
  int sel = blockIdx.y;
  const float* src = (sel == 0) ? W0 : (sel == 1) ? W1 : (sel == 2) ? W2 : W3;
  unsigned short* d = dst + (size_t)sel * HID * HID;
  int i = (blockIdx.x * 256 + threadIdx.x) * 4;
  float4 v = *(const float4*)(src + i);
  ushort4 o;
  o.x = f2bf(v.x); o.y = f2bf(v.y); o.z = f2bf(v.z); o.w = f2bf(v.w);
  *(ushort4*)(d + i) = o;
}

// ---------------- GEMM 1: QKV projection, persistent 256-block, 3x(256x128) passes ----
// (R5 structure, unchanged: static buffer rotation, 1 barrier/phase, vmcnt(6) FIFO)
#define BUFU (24576)   // ushorts per buffer (48KB): A 16384 + B 8192
#define BUF3 (3 * BUFU)

__global__ __launch_bounds__(512, 2) void gemm_qkv384_kernel(
    const unsigned short* __restrict__ Xb, const unsigned short* __restrict__ Wb,
    const float* __restrict__ bq, const float* __restrict__ bk,
    const float* __restrict__ bv, unsigned short* __restrict__ Cout) {
  __shared__ __align__(16) unsigned short smem[BUF3];   // 144 KiB

  const int tid  = threadIdx.x;
  const int w    = tid >> 6;
  const int lane = tid & 63;
  const int l16  = lane & 15;
  const int quad = lane >> 4;
  const int wm   = (w & 3) * 64;    // 4 M-waves
  const int wn   = (w >> 2) * 64;   // 2 N-waves

  const int wg = blockIdx.x;
  const int sw = (wg & 7) * 32 + (wg >> 3);
  const int m0  = (sw & 15) * 256;
  const int rn0 = (sw >> 4) * 384;

  const int sr  = tid >> 3;
  const int scs = ((tid & 7) ^ (sr & 7)) * 8;
  const unsigned short* aBase = Xb + (size_t)(m0 + sr) * HID + scs;

#define STGA(UB, RB, KT)                                              \
  async16(aBase + (size_t)(RB) * HID + (KT),                          \
          (char*)smem + (UB) * 2 + (RB) * 128 + w * 1024)
#define STGB(UB, RB, KT)                                              \
  async16(bBase + (size_t)(RB) * HID + (KT),                          \
          (char*)smem + (UB) * 2 + 32768 + (RB) * 128 + w * 1024)

#define VM6  asm volatile("s_waitcnt vmcnt(6)" ::: "memory")
#define VM0  asm volatile("s_waitcnt vmcnt(0)" ::: "memory")

#define PHASE(UB, KK, STGBLK, WAITBLK)                                         \
  {                                                                            \
    const unsigned short* Ab = smem + (UB);                                    \
    const unsigned short* Bb = Ab + 16384;                                     \
    bf16x8 ta[4], tb[4];                                                       \
    ta[0] = frag(Ab, wm + l16, (KK) * 4 + quad);                               \
    _Pragma("unroll")                                                          \
    for (int j = 0; j < 4; ++j)  tb[j] = frag(Bb, wn + j * 16 + l16, (KK) * 4 + quad); \
    _Pragma("unroll")                                                          \
    for (int ii = 1; ii < 4; ++ii) ta[ii] = frag(Ab, wm + ii * 16 + l16, (KK) * 4 + quad); \
    STGBLK;                                                                    \
    __builtin_amdgcn_s_setprio(1);                                             \
    _Pragma("unroll")                                                          \
    for (int ii = 0; ii < 4; ++ii)                                             \
      _Pragma("unroll")                                                        \
      for (int j = 0; j < 4; ++j) mfma16(acc[ii][j], ta[ii], tb[j]);           \
    __builtin_amdgcn_s_setprio(0);                                             \
    asm volatile("s_waitcnt lgkmcnt(0)" ::: "memory");                         \
    WAITBLK;                                                                   \
    __builtin_amdgcn_s_barrier();                                              \
  }

  for (int p = 0; p < 3; ++p) {
    const unsigned short* bBase = Wb + (size_t)(rn0 + p * 128 + sr) * HID + scs;

    f32x4 acc[4][4];
    const f32x4 zero = {0.f, 0.f, 0.f, 0.f};
#pragma unroll
    for (int a = 0; a < 4; ++a)
#pragma unroll
      for (int j = 0; j < 4; ++j) acc[a][j] = zero;

    STGA(0, 0, 0);  STGA(0, 64, 0);  STGA(0, 128, 0);  STGA(0, 192, 0);
    STGB(0, 0, 0);  STGB(0, 64, 0);
    STGA(BUFU, 0, 64);  STGA(BUFU, 64, 64);  STGA(BUFU, 128, 64);  STGA(BUFU, 192, 64);
    STGB(BUFU, 0, 64);  STGB(BUFU, 64, 64);
    VM6;
    __builtin_amdgcn_s_barrier();

    int kb = 0;
    for (int g = 0; g < 5; ++g) {
      PHASE(0,        0, { STGA(2*BUFU, 0, kb+128); STGA(2*BUFU, 64, kb+128); STGA(2*BUFU, 128, kb+128); }, {});
      PHASE(0,        1, { STGA(2*BUFU, 192, kb+128); STGB(2*BUFU, 0, kb+128); STGB(2*BUFU, 64, kb+128); }, VM6);
      PHASE(BUFU,     0, { STGA(0, 0, kb+192); STGA(0, 64, kb+192); STGA(0, 128, kb+192); }, {});
      PHASE(BUFU,     1, { STGA(0, 192, kb+192); STGB(0, 0, kb+192); STGB(0, 64, kb+192); }, VM6);
      PHASE(2*BUFU,   0, { STGA(BUFU, 0, kb+256); STGA(BUFU, 64, kb+256); STGA(BUFU, 128, kb+256); }, {});
      PHASE(2*BUFU,   1, { STGA(BUFU, 192, kb+256); STGB(BUFU, 0, kb+256); STGB(BUFU, 64, kb+256); }, VM6);
      PHASE(0,        0, { STGA(2*BUFU, 0, kb+320); STGA(2*BUFU, 64, kb+320); STGA(2*BUFU, 128, kb+320); }, {});
      PHASE(0,        1, { STGA(2*BUFU, 192, kb+320); STGB(2*BUFU, 0, kb+320); STGB(2*BUFU, 64, kb+320); }, VM6);
      PHASE(BUFU,     0, { STGA(0, 0, kb+384); STGA(0, 64, kb+384); STGA(0, 128, kb+384); }, {});
      PHASE(BUFU,     1, { STGA(0, 192, kb+384); STGB(0, 0, kb+384); STGB(0, 64, kb+384); }, VM6);
      PHASE(2*BUFU,   0, { STGA(BUFU, 0, kb+448); STGA(BUFU, 64, kb+448); STGA(BUFU, 128, kb+448); }, {});
      PHASE(2*BUFU,   1, { STGA(BUFU, 192, kb+448); STGB(BUFU, 0, kb+448); STGB(BUFU, 64, kb+448); }, VM6);
      kb += 384;
    }

    PHASE(0,    0, {}, {});
    PHASE(0,    1, {}, VM0);
    PHASE(BUFU, 0, {}, {});
    PHASE(BUFU, 1, {}, {});

#pragma unroll
    for (int j = 0; j < 4; ++j) {
      int ng = rn0 + p * 128 + wn + j * 16 + l16;
      float bias = (ng < HID) ? bq[ng] : (ng < 2 * HID ? bk[ng - HID] : bv[ng - 2 * HID]);
#pragma unroll
      for (int a = 0; a < 4; ++a)
#pragma unroll
        for (int r = 0; r < 4; ++r) {
          int mg = m0 + wm + a * 16 + quad * 4 + r;
          Cout[(size_t)mg * NQKV + ng] = f2bf(acc[a][j][r] + bias);
        }
    }
  }
#undef STGA
#undef STGB
#undef PHASE
#undef VM6
#undef VM0
}

// ---------------- GEMM 2: out-proj, SAME persistent structure (single pass) ----------------
// 256 blocks x (256x128 region); K=2048; epilogue fp32 + bias + residual.
__global__ __launch_bounds__(512, 2) void gemm_out384_kernel(
    const unsigned short* __restrict__ Ctx, const unsigned short* __restrict__ Wdb,
    const float* __restrict__ bd, const float* __restrict__ Res,
    float* __restrict__ Out) {
  __shared__ __align__(16) unsigned short smem[BUF3];   // 144 KiB

  const int tid  = threadIdx.x;
  const int w    = tid >> 6;
  const int lane = tid & 63;
  const int l16  = lane & 15;
  const int quad = lane >> 4;
  const int wm   = (w & 3) * 64;
  const int wn   = (w >> 2) * 64;

  const int wg = blockIdx.x;
  const int sw = (wg & 7) * 32 + (wg >> 3);
  const int m0  = (sw & 15) * 256;
  const int rn0 = (sw >> 4) * 128;

  const int sr  = tid >> 3;
  const int scs = ((tid & 7) ^ (sr & 7)) * 8;
  const unsigned short* aBase = Ctx + (size_t)(m0 + sr) * HID + scs;
  const unsigned short* bBase = Wdb + (size_t)(rn0 + sr) * HID + scs;

#define STGA(UB, RB, KT)                                              \
  async16(aBase + (size_t)(RB) * HID + (KT),                          \
          (char*)smem + (UB) * 2 + (RB) * 128 + w * 1024)
#define STGB(UB, RB, KT)                                              \
  async16(bBase + (size_t)(RB) * HID + (KT),                          \
          (char*)smem + (UB) * 2 + 32768 + (RB) * 128 + w * 1024)

#define VM6  asm volatile("s_waitcnt vmcnt(6)" ::: "memory")
#define VM0  asm volatile("s_waitcnt vmcnt(0)" ::: "memory")

#define PHASE(UB, KK, STGBLK, WAITBLK)                                         \
  {                                                                            \
    const unsigned short* Ab = smem + (UB);                                    \
    const unsigned short* Bb = Ab + 16384;                                     \
    bf16x8 ta[4], tb[4];                                                       \
    ta[0] = frag(Ab, wm + l16, (KK) * 4 + quad);                               \
    _Pragma("unroll")                                                          \
    for (int j = 0; j < 4; ++j)  tb[j] = frag(Bb, wn + j * 16 + l16, (KK) * 4 + quad); \
    _Pragma("unroll")                                                          \
    for (int ii = 1; ii < 4; ++ii) ta[ii] = frag(Ab, wm + ii * 16 + l16, (KK) * 4 + quad); \
    STGBLK;                                                                    \
    __builtin_amdgcn_s_setprio(1);                                             \
    _Pragma("unroll")                                                          \
    for (int ii = 0; ii < 4; ++ii)                                             \
      _Pragma("unroll")                                                        \
      for (int j = 0; j < 4; ++j) mfma16(acc[ii][j], ta[ii], tb[j]);           \
    __builtin_amdgcn_s_setprio(0);                                             \
    asm volatile("s_waitcnt lgkmcnt(0)" ::: "memory");                         \
    WAITBLK;                                                                   \
    __builtin_amdgcn_s_barrier();                                              \
  }

  f32x4 acc[4][4];
  const f32x4 zero = {0.f, 0.f, 0.f, 0.f};
#pragma unroll
  for (int a = 0; a < 4; ++a)
#pragma unroll
    for (int j = 0; j < 4; ++j) acc[a][j] = zero;

  STGA(0, 0, 0);  STGA(0, 64, 0);  STGA(0, 128, 0);  STGA(0, 192, 0);
  STGB(0, 0, 0);  STGB(0, 64, 0);
  STGA(BUFU, 0, 64);  STGA(BUFU, 64, 64);  STGA(BUFU, 128, 64);  STGA(BUFU, 192, 64);
  STGB(BUFU, 0, 64);  STGB(BUFU, 64, 64);
  VM6;
  __builtin_amdgcn_s_barrier();

  int kb = 0;
  for (int g = 0; g < 5; ++g) {
    PHASE(0,        0, { STGA(2*BUFU, 0, kb+128); STGA(2*BUFU, 64, kb+128); STGA(2*BUFU, 128, kb+128); }, {});
    PHASE(0,        1, { STGA(2*BUFU, 192, kb+128); STGB(2*BUFU, 0, kb+128); STGB(2*BUFU, 64, kb+128); }, VM6);
    PHASE(BUFU,     0, { STGA(0, 0, kb+192); STGA(0, 64, kb+192); STGA(0, 128, kb+192); }, {});
    PHASE(BUFU,     1, { STGA(0, 192, kb+192); STGB(0, 0, kb+192); STGB(0, 64, kb+192); }, VM6);
    PHASE(2*BUFU,   0, { STGA(BUFU, 0, kb+256); STGA(BUFU, 64, kb+256); STGA(BUFU, 128, kb+256); }, {});
    PHASE(2*BUFU,   1, { STGA(BUFU, 192, kb+256); STGB(BUFU, 0, kb+256); STGB(BUFU, 64, kb+256); }, VM6);
    PHASE(0,        0, { STGA(2*BUFU, 0, kb+320); STGA(2*BUFU, 64, kb+320); STGA(2*BUFU, 128, kb+320); }, {});
    PHASE(0,        1, { STGA(2*BUFU, 192, kb+320); STGB(2*BUFU, 0, kb+320); STGB(2*BUFU, 64, kb+320); }, VM6);
    PHASE(BUFU,     0, { STGA(0, 0, kb+384); STGA(0, 64, kb+384); STGA(0, 128, kb+384); }, {});
    PHASE(BUFU,     1, { STGA(0, 192, kb+384); STGB(0, 0, kb+384); STGB(0, 64, kb+384); }, VM6);
    PHASE(2*BUFU,   0, { STGA(BUFU, 0, kb+448); STGA(BUFU, 64, kb+448); STGA(BUFU, 128, kb+448); }, {});
    PHASE(2*BUFU,   1, { STGA(BUFU, 192, kb+448); STGB(BUFU, 0, kb+448); STGB(BUFU, 64, kb+448); }, VM6);
    kb += 384;
  }

  PHASE(0,    0, {}, {});
  PHASE(0,    1, {}, VM0);
  PHASE(BUFU, 0, {}, {});
  PHASE(BUFU, 1, {}, {});

#pragma unroll
  for (int j = 0; j < 4; ++j) {
    int ng = rn0 + wn + j * 16 + l16;
    float bias = bd[ng];
#pragma unroll
    for (int a = 0; a < 4; ++a)
#pragma unroll
      for (int r = 0; r < 4; ++r) {
        int mg = m0 + wm + a * 16 + quad * 4 + r;
        size_t off = (size_t)mg * HID + ng;
        Out[off] = acc[a][j][r] + bias + Res[off];
      }
  }
#undef STGA
#undef STGB
#undef PHASE
#undef VM6
#undef VM0
}

// ---------------- V transpose: QKV V-part -> Vt[bh][d][s] ----------------
__global__ __launch_bounds__(256) void vtrans_kernel(const unsigned short* __restrict__ QKV,
                                                     unsigned short* __restrict__ Vt) {
  __shared__ __align__(16) unsigned short T[64][72];
  const int s0 = blockIdx.x * 64, d0 = blockIdx.y * 64, bh = blockIdx.z;
  const int b = bh >> 4, h = bh & 15;
  const int tid = threadIdx.x;
#pragma unroll
  for (int i = 0; i < 2; ++i) {
    int idx = i * 256 + tid;
    int r = idx >> 3, ch = idx & 7;
    const unsigned short* g = QKV + ((size_t)b * SEQ + s0 + r) * NQKV + 2 * HID + h * HD + d0 + ch * 8;
    *(uint4*)(&T[r][ch * 8]) = *(const uint4*)g;
  }
  __syncthreads();
#pragma unroll
  for (int i = 0; i < 2; ++i) {
    int idx = i * 256 + tid;
    int d = idx >> 3, ch = idx & 7;
    unsigned short v[8];
#pragma unroll
    for (int x = 0; x < 8; ++x) v[x] = T[ch * 8 + x][d];
    unsigned short* g = Vt + ((size_t)bh * HD + d0 + d) * SEQ + s0 + ch * 8;
    *(uint4*)g = *(const uint4*)v;
  }
}

// ---------------- flash attention, 32x32 MFMA, S^T trick, T14 pipeline ----------------
// grid = (SEQ/128, BATCH*NHEAD); block 256 (4 waves, 32 q-rows each).
// LDS: Ks 16KB | Vts0 16KB | Vts1 16KB (V dbuf) | Ps 18KB | Als (alibi) 8KB = 75.8KB
// -> 2 blocks/CU. Per iter: QK^T -> lgkm(0)+barrier (K WAR-free) -> ISSUE K/V(t+1)
// asyncs -> softmax (alibi from LDS, broadcast) -> PV on V[t&1] -> vmcnt(0)+barrier.
// Asyncs drain ~softmax+PV (>600cyc) after issue: latency hidden (T14). setprio (T5).
__global__ __launch_bounds__(256, 2) void attn_kernel(
    const unsigned short* __restrict__ QKV, const unsigned short* __restrict__ Vt,
    const float* __restrict__ alibi, unsigned short* __restrict__ Ctx) {
  __shared__ __align__(16) char smem[75776];
  unsigned short* Ks   = (unsigned short*)smem;
  unsigned short* Vts0 = (unsigned short*)(smem + 16384);
  unsigned short* Vts1 = (unsigned short*)(smem + 32768);
  unsigned short* Ps   = (unsigned short*)(smem + 49152);
  float*          Alsf = (float*)(smem + 67584);
  unsigned short* Qs   = (unsigned short*)smem;   // alias: Q staging (32 KB over Ks+Vts0)

  const int tid = threadIdx.x, w = tid >> 6, lane = tid & 63;
  const int l32 = lane & 31, h = lane >> 5;
  const int q0 = blockIdx.x * 128;
  const int bh = blockIdx.y, b = bh >> 4, hh = bh & 15;
  const size_t rowbase = (size_t)b * SEQ;
  const float* ali = alibi + (size_t)bh * SEQ;
  const unsigned short* Vbh = Vt + (size_t)bh * HD * SEQ;

  // ---- stage Q (aliases Ks+Vts0) + alibi row (8KB) ----
  {
    const unsigned short* qbase = QKV + (rowbase + q0) * NQKV + hh * HD;
#pragma unroll
    for (int i = 0; i < 8; ++i) {
      int slot = i * 256 + w * 64 + lane;
      int r = slot >> 4, c = (slot & 15) ^ (r & 15);
      async16(qbase + (size_t)r * NQKV + c * 8, (char*)Qs + (size_t)(i * 256 + w * 64) * 16);
    }
    const char* asrc = (const char*)ali;
#pragma unroll
    for (int i = 0; i < 2; ++i) {
      int slot = i * 256 + w * 64 + lane;
      async16(asrc + (size_t)slot * 16, (char*)Alsf + (size_t)(i * 256 + w * 64) * 16);
    }
  }
  __syncthreads();
  bf16x8 qf[8];
  {
    int qr = w * 32 + l32;
#pragma unroll
    for (int ks = 0; ks < 8; ++ks) {
      int c = (ks * 2 + h) ^ (qr & 15);
      qf[ks] = *(const bf16x8*)(Qs + (qr * 16 + c) * 8);
    }
  }

  f32x16 oacc[4];
  float l_acc = 0.f;
#pragma unroll
  for (int nb = 0; nb < 4; ++nb)
#pragma unroll
    for (int r = 0; r < 16; ++r) oacc[nb][r] = 0.f;

  __syncthreads();   // qf reads complete before K0 staging overwrites alias

  // ---- stage K(0) -> Ks, V(0) -> Vts0 ----
  {
    const unsigned short* kbase = QKV + rowbase * NQKV + HID + hh * HD;
#pragma unroll
    for (int i = 0; i < 4; ++i) {
      int slot = i * 256 + w * 64 + lane;
      int r = slot >> 4, c = (slot & 15) ^ (r & 15);
      async16(kbase + (size_t)r * NQKV + c * 8, (char*)Ks + (size_t)(i * 256 + w * 64) * 16);
    }
#pragma unroll
    for (int i = 0; i < 4; ++i) {
      int slot = i * 256 + w * 64 + lane;
      int r = slot >> 3, c = (slot & 7) ^ (r & 7);
      async16(Vbh + (size_t)r * SEQ + c * 8, (char*)Vts0 + (size_t)(i * 256 + w * 64) * 16);
    }
  }
  __syncthreads();

  for (int kt = 0; kt < SEQ / 64; ++kt) {
    // ---- S^T = K Q^T on current K tile ----
    f32x16 sacc[2];
#pragma unroll
    for (int mb = 0; mb < 2; ++mb)
#pragma unroll
      for (int r = 0; r < 16; ++r) sacc[mb][r] = 0.f;
    __builtin_amdgcn_s_setprio(1);
#pragma unroll
    for (int ks = 0; ks < 8; ++ks) {
#pragma unroll
      for (int mb = 0; mb < 2; ++mb) {
        bf16x8 kf = *(const bf16x8*)(Ks + ((mb * 32 + l32) * 16 + ((ks * 2 + h) ^ (l32 & 15))) * 8);
        sacc[mb] = __builtin_amdgcn_mfma_f32_32x32x16_bf16(kf, qf[ks], sacc[mb], 0, 0, 0);
      }
    }
    __builtin_amdgcn_s_setprio(0);
    asm volatile("s_waitcnt lgkmcnt(0)" ::: "memory");
    __builtin_amdgcn_s_barrier();            // all K-reads done -> Ks free

    // ---- issue K(t+1) -> Ks, V(t+1) -> Vts[(t+1)&1] (drain at iter end) ----
    if (kt + 1 < SEQ / 64) {
      const unsigned short* kbase = QKV + (rowbase + (kt + 1) * 64) * NQKV + HID + hh * HD;
#pragma unroll
      for (int i = 0; i < 4; ++i) {
        int slot = i * 256 + w * 64 + lane;
        int r = slot >> 4, c = (slot & 15) ^ (r & 15);
        async16(kbase + (size_t)r * NQKV + c * 8, (char*)Ks + (size_t)(i * 256 + w * 64) * 16);
      }
      const unsigned short* vbase = Vbh + (kt + 1) * 64;
      unsigned short* vdst = ((kt + 1) & 1) ? Vts1 : Vts0;
#pragma unroll
      for (int i = 0; i < 4; ++i) {
        int slot = i * 256 + w * 64 + lane;
        int r = slot >> 3, c = (slot & 7) ^ (r & 7);
        async16(vbase + (size_t)r * SEQ + c * 8, (char*)vdst + (size_t)(i * 256 + w * 64) * 16);
      }
    }

    // ---- softmax (fixed-max): alibi from LDS (broadcast reads, no VMEM) ----
    const int qrow = w * 32 + l32;
    const float* alsk = Alsf + kt * 64 + 4 * h;
#pragma unroll
    for (int mb = 0; mb < 2; ++mb) {
#pragma unroll
      for (int g = 0; g < 4; ++g) {
        float4 av = *(const float4*)(alsk + mb * 32 + g * 8);
        float p0 = __builtin_amdgcn_exp2f(sacc[mb][g * 4 + 0] * SCALE_L2 + av.x * LOG2E);
        float p1 = __builtin_amdgcn_exp2f(sacc[mb][g * 4 + 1] * SCALE_L2 + av.y * LOG2E);
        float p2 = __builtin_amdgcn_exp2f(sacc[mb][g * 4 + 2] * SCALE_L2 + av.z * LOG2E);
        float p3 = __builtin_amdgcn_exp2f(sacc[mb][g * 4 + 3] * SCALE_L2 + av.w * LOG2E);
        l_acc += (p0 + p1) + (p2 + p3);
        uint2 pk;
        pk.x = pkbf(p0, p1);
        pk.y = pkbf(p2, p3);
        *(uint2*)(Ps + qrow * 72 + mb * 32 + g * 8 + 4 * h) = pk;
      }
    }

    // ---- O += P V on V(t) ----
    const unsigned short* vcur = (kt & 1) ? Vts1 : Vts0;
    __builtin_amdgcn_s_setprio(1);
#pragma unroll
    for (int ks2 = 0; ks2 < 4; ++ks2) {
      bf16x8 pf = *(const bf16x8*)(Ps + qrow * 72 + ks2 * 16 + h * 8);
#pragma unroll
      for (int nb = 0; nb < 4; ++nb) {
        bf16x8 vf = *(const bf16x8*)(vcur + ((nb * 32 + l32) * 8 + ((ks2 * 2 + h) ^ (l32 & 7))) * 8);
        oacc[nb] = __builtin_amdgcn_mfma_f32_32x32x16_bf16(pf, vf, oacc[nb], 0, 0, 0);
      }
    }
    __builtin_amdgcn_s_setprio(0);

    asm volatile("s_waitcnt lgkmcnt(0) vmcnt(0)" ::: "memory");
    __builtin_amdgcn_s_barrier();            // K(t+1)/V(t+1) visible
  }

  float lf = l_acc + __shfl_xor(l_acc, 32, 64);
  float rinv[16];
#pragma unroll
  for (int reg = 0; reg < 16; ++reg) {
    int row = (reg & 3) + 8 * (reg >> 2) + 4 * h;
    rinv[reg] = 1.0f / __shfl(lf, row, 64);
  }

#pragma unroll
  for (int nb = 0; nb < 4; ++nb)
#pragma unroll
    for (int reg = 0; reg < 16; ++reg) {
      int row = (reg & 3) + 8 * (reg >> 2) + 4 * h;
      size_t qg = rowbase + q0 + w * 32 + row;
      Ctx[qg * HID + hh * HD + nb * 32 + l32] = f2bf(oacc[nb][reg] * rinv[reg]);
    }
}

// ---------------- launch ----------------
extern "C" void kernel_launch(void* const* d_in, const int* in_sizes, int n_in,
                              void* d_out, int out_size, void* d_ws, size_t ws_size,
                              hipStream_t stream) {
  const float* hidden   = (const float*)d_in[0];
  const float* residual = (const float*)d_in[1];
  const float* alibi    = (const float*)d_in[2];
  const float* Wq = (const float*)d_in[3];
  const float* bq = (const float*)d_in[4];
  const float* Wk = (const float*)d_in[5];
  const float* bk = (const float*)d_in[6];
  const float* Wv = (const float*)d_in[7];
  const float* bv = (const float*)d_in[8];
  const float* Wd = (const float*)d_in[9];
  const float* bd = (const float*)d_in[10];
  float* out = (float*)d_out;

  unsigned short* Xb    = (unsigned short*)d_ws;                    // 4096*2048
  unsigned short* Wqkvb = Xb + (size_t)MROWS * HID;                 // 6144*2048
  unsigned short* Wdb   = Wqkvb + (size_t)NQKV * HID;               // 2048*2048
  unsigned short* QKVb  = Wdb + (size_t)HID * HID;                  // 4096*6144
  unsigned short* Ctxb  = QKVb + (size_t)MROWS * NQKV;              // 4096*2048
  unsigned short* Vtb   = Wqkvb;  // Vt reuses Wqkvb region (dead after gemm_qkv)

  const int nX = MROWS * HID, nW = HID * HID;
  cvt_kernel<<<nX / 4 / 256, 256, 0, stream>>>(hidden, Xb, nX);
  cvtw_kernel<<<dim3(nW / 4 / 256, 4), 256, 0, stream>>>(Wq, Wk, Wv, Wd, Wqkvb);

  gemm_qkv384_kernel<<<256, 512, 0, stream>>>(Xb, Wqkvb, bq, bk, bv, QKVb);
  vtrans_kernel<<<dim3(SEQ / 64, HD / 64, BATCH * NHEAD), 256, 0, stream>>>(QKVb, Vtb);
  attn_kernel<<<dim3(SEQ / 128, BATCH * NHEAD), 256, 0, stream>>>(QKVb, Vtb, alibi, Ctxb);
  gemm_out384_kernel<<<256, 512, 0, stream>>>(Ctxb, Wdb, bd, residual, out);
}

// Round 7
// 439.018 us; speedup vs baseline: 1.0115x; 1.0115x over previous
//
#include <hip/hip_runtime.h>

// ---------------- problem constants ----------------
#define HID   2048
#define NHEAD 16
#define HD    128
#define SEQ   2048
#define BATCH 2
#define MROWS (BATCH*SEQ)        // 4096
#define NQKV  (3*HID)            // 6144
#define INV_NORM 0.08838834764831845f
#define LOG2E    1.4426950408889634f
#define SCALE_L2 (INV_NORM*LOG2E)

typedef __attribute__((ext_vector_type(8)))  __bf16 bf16x8;
typedef __attribute__((ext_vector_type(4)))  float  f32x4;
typedef __attribute__((ext_vector_type(16))) float  f32x16;

typedef __attribute__((address_space(1))) void GV;
typedef __attribute__((address_space(3))) void LV;

__device__ __forceinline__ void async16(const void* g, void* l) {
  __builtin_amdgcn_global_load_lds((const GV*)g, (LV*)l, 16, 0, 0);
}

__device__ __forceinline__ unsigned short f2bf(float f) {
  unsigned u = __builtin_bit_cast(unsigned, f);
  u += 0x7FFFu + ((u >> 16) & 1u);       // RNE
  return (unsigned short)(u >> 16);
}

__device__ __forceinline__ unsigned pkbf(float a, float b) {
#if __has_builtin(__builtin_amdgcn_cvt_pk_bf16_f32)
  typedef __attribute__((ext_vector_type(2))) __bf16 bf16x2;
  bf16x2 r = __builtin_amdgcn_cvt_pk_bf16_f32(a, b);
  return __builtin_bit_cast(unsigned, r);
#else
  return (unsigned)f2bf(a) | ((unsigned)f2bf(b) << 16);
#endif
}

// exchange a's upper 32 lanes with b's lower 32 lanes (v_permlane32_swap_b32 a, b)
__device__ __forceinline__ void pl32swap(unsigned &a, unsigned &b) {
#if __has_builtin(__builtin_amdgcn_permlane32_swap)
  typedef __attribute__((ext_vector_type(2))) unsigned u32x2;
  u32x2 r = __builtin_amdgcn_permlane32_swap(a, b, false, false);
  a = r[0]; b = r[1];
#else
  asm volatile("v_permlane32_swap_b32 %0, %1" : "+v"(a), "+v"(b));
#endif
}

__device__ __forceinline__ void mfma16(f32x4& c, bf16x8 a, bf16x8 b) {
  c = __builtin_amdgcn_mfma_f32_16x16x32_bf16(a, b, c, 0, 0, 0);
}

// LDS fragment read with chunk-XOR swizzle (BK=64 -> 8 chunks of 16B per row)
__device__ __forceinline__ bf16x8 frag(const unsigned short* buf, int row, int chunk) {
  return *(const bf16x8*)(buf + ((row * 8 + (chunk ^ (row & 7))) << 3));
}

// ---------------- fp32 -> bf16 casts ----------------
__global__ __launch_bounds__(256) void cvt_kernel(const float* __restrict__ src,
                                                  unsigned short* __restrict__ dst, int n) {
  int i = (blockIdx.x * 256 + threadIdx.x) * 4;
  if (i >= n) return;
  float4 v = *(const float4*)(src + i);
  ushort4 o;
  o.x = f2bf(v.x); o.y = f2bf(v.y); o.z = f2bf(v.z); o.w = f2bf(v.w);
  *(ushort4*)(dst + i) = o;
}

__global__ __launch_bounds__(256) void cvtw_kernel(const float* __restrict__ W0,
                                                   const float* __restrict__ W1,
                                                   const float* __restrict__ W2,
                                                   const float* __restrict__ W3,
                                                   unsigned short* __restrict__ dst) {
  int sel = blockIdx.y;
  const float* src = (sel == 0) ? W0 : (sel == 1) ? W1 : (sel == 2) ? W2 : W3;
  unsigned short* d = dst + (size_t)sel * HID * HID;
  int i = (blockIdx.x * 256 + threadIdx.x) * 4;
  float4 v = *(const float4*)(src + i);
  ushort4 o;
  o.x = f2bf(v.x); o.y = f2bf(v.y); o.z = f2bf(v.z); o.w = f2bf(v.w);
  *(ushort4*)(d + i) = o;
}

// ---------------- GEMM 1: QKV projection, persistent 256-block, 3x(256x128) passes ----
// (R5 structure, unchanged: static buffer rotation, 1 barrier/phase, vmcnt(6) FIFO)
#define BUFU (24576)   // ushorts per buffer (48KB): A 16384 + B 8192
#define BUF3 (3 * BUFU)

__global__ __launch_bounds__(512, 2) void gemm_qkv384_kernel(
    const unsigned short* __restrict__ Xb, const unsigned short* __restrict__ Wb,
    const float* __restrict__ bq, const float* __restrict__ bk,
    const float* __restrict__ bv, unsigned short* __restrict__ Cout) {
  __shared__ __align__(16) unsigned short smem[BUF3];   // 144 KiB

  const int tid  = threadIdx.x;
  const int w    = tid >> 6;
  const int lane = tid & 63;
  const int l16  = lane & 15;
  const int quad = lane >> 4;
  const int wm   = (w & 3) * 64;    // 4 M-waves
  const int wn   = (w >> 2) * 64;   // 2 N-waves

  const int wg = blockIdx.x;
  const int sw = (wg & 7) * 32 + (wg >> 3);
  const int m0  = (sw & 15) * 256;
  const int rn0 = (sw >> 4) * 384;

  const int sr  = tid >> 3;
  const int scs = ((tid & 7) ^ (sr & 7)) * 8;
  const unsigned short* aBase = Xb + (size_t)(m0 + sr) * HID + scs;

#define STGA(UB, RB, KT)                                              \
  async16(aBase + (size_t)(RB) * HID + (KT),                          \
          (char*)smem + (UB) * 2 + (RB) * 128 + w * 1024)
#define STGB(UB, RB, KT)                                              \
  async16(bBase + (size_t)(RB) * HID + (KT),                          \
          (char*)smem + (UB) * 2 + 32768 + (RB) * 128 + w * 1024)

#define VM6  asm volatile("s_waitcnt vmcnt(6)" ::: "memory")
#define VM0  asm volatile("s_waitcnt vmcnt(0)" ::: "memory")

#define PHASE(UB, KK, STGBLK, WAITBLK)                                         \
  {                                                                            \
    const unsigned short* Ab = smem + (UB);                                    \
    const unsigned short* Bb = Ab + 16384;                                     \
    bf16x8 ta[4], tb[4];                                                       \
    ta[0] = frag(Ab, wm + l16, (KK) * 4 + quad);                               \
    _Pragma("unroll")                                                          \
    for (int j = 0; j < 4; ++j)  tb[j] = frag(Bb, wn + j * 16 + l16, (KK) * 4 + quad); \
    _Pragma("unroll")                                                          \
    for (int ii = 1; ii < 4; ++ii) ta[ii] = frag(Ab, wm + ii * 16 + l16, (KK) * 4 + quad); \
    STGBLK;                                                                    \
    __builtin_amdgcn_s_setprio(1);                                             \
    _Pragma("unroll")                                                          \
    for (int ii = 0; ii < 4; ++ii)                                             \
      _Pragma("unroll")                                                        \
      for (int j = 0; j < 4; ++j) mfma16(acc[ii][j], ta[ii], tb[j]);           \
    __builtin_amdgcn_s_setprio(0);                                             \
    asm volatile("s_waitcnt lgkmcnt(0)" ::: "memory");                         \
    WAITBLK;                                                                   \
    __builtin_amdgcn_s_barrier();                                              \
  }

  for (int p = 0; p < 3; ++p) {
    const unsigned short* bBase = Wb + (size_t)(rn0 + p * 128 + sr) * HID + scs;

    f32x4 acc[4][4];
    const f32x4 zero = {0.f, 0.f, 0.f, 0.f};
#pragma unroll
    for (int a = 0; a < 4; ++a)
#pragma unroll
      for (int j = 0; j < 4; ++j) acc[a][j] = zero;

    STGA(0, 0, 0);  STGA(0, 64, 0);  STGA(0, 128, 0);  STGA(0, 192, 0);
    STGB(0, 0, 0);  STGB(0, 64, 0);
    STGA(BUFU, 0, 64);  STGA(BUFU, 64, 64);  STGA(BUFU, 128, 64);  STGA(BUFU, 192, 64);
    STGB(BUFU, 0, 64);  STGB(BUFU, 64, 64);
    VM6;
    __builtin_amdgcn_s_barrier();

    int kb = 0;
    for (int g = 0; g < 5; ++g) {
      PHASE(0,        0, { STGA(2*BUFU, 0, kb+128); STGA(2*BUFU, 64, kb+128); STGA(2*BUFU, 128, kb+128); }, {});
      PHASE(0,        1, { STGA(2*BUFU, 192, kb+128); STGB(2*BUFU, 0, kb+128); STGB(2*BUFU, 64, kb+128); }, VM6);
      PHASE(BUFU,     0, { STGA(0, 0, kb+192); STGA(0, 64, kb+192); STGA(0, 128, kb+192); }, {});
      PHASE(BUFU,     1, { STGA(0, 192, kb+192); STGB(0, 0, kb+192); STGB(0, 64, kb+192); }, VM6);
      PHASE(2*BUFU,   0, { STGA(BUFU, 0, kb+256); STGA(BUFU, 64, kb+256); STGA(BUFU, 128, kb+256); }, {});
      PHASE(2*BUFU,   1, { STGA(BUFU, 192, kb+256); STGB(BUFU, 0, kb+256); STGB(BUFU, 64, kb+256); }, VM6);
      PHASE(0,        0, { STGA(2*BUFU, 0, kb+320); STGA(2*BUFU, 64, kb+320); STGA(2*BUFU, 128, kb+320); }, {});
      PHASE(0,        1, { STGA(2*BUFU, 192, kb+320); STGB(2*BUFU, 0, kb+320); STGB(2*BUFU, 64, kb+320); }, VM6);
      PHASE(BUFU,     0, { STGA(0, 0, kb+384); STGA(0, 64, kb+384); STGA(0, 128, kb+384); }, {});
      PHASE(BUFU,     1, { STGA(0, 192, kb+384); STGB(0, 0, kb+384); STGB(0, 64, kb+384); }, VM6);
      PHASE(2*BUFU,   0, { STGA(BUFU, 0, kb+448); STGA(BUFU, 64, kb+448); STGA(BUFU, 128, kb+448); }, {});
      PHASE(2*BUFU,   1, { STGA(BUFU, 192, kb+448); STGB(BUFU, 0, kb+448); STGB(BUFU, 64, kb+448); }, VM6);
      kb += 384;
    }

    PHASE(0,    0, {}, {});
    PHASE(0,    1, {}, VM0);
    PHASE(BUFU, 0, {}, {});
    PHASE(BUFU, 1, {}, {});

#pragma unroll
    for (int j = 0; j < 4; ++j) {
      int ng = rn0 + p * 128 + wn + j * 16 + l16;
      float bias = (ng < HID) ? bq[ng] : (ng < 2 * HID ? bk[ng - HID] : bv[ng - 2 * HID]);
#pragma unroll
      for (int a = 0; a < 4; ++a)
#pragma unroll
        for (int r = 0; r < 4; ++r) {
          int mg = m0 + wm + a * 16 + quad * 4 + r;
          Cout[(size_t)mg * NQKV + ng] = f2bf(acc[a][j][r] + bias);
        }
    }
  }
#undef STGA
#undef STGB
#undef PHASE
#undef VM6
#undef VM0
}

// ---------------- GEMM 2: out-proj, SAME persistent structure (single pass) ----------------
__global__ __launch_bounds__(512, 2) void gemm_out384_kernel(
    const unsigned short* __restrict__ Ctx, const unsigned short* __restrict__ Wdb,
    const float* __restrict__ bd, const float* __restrict__ Res,
    float* __restrict__ Out) {
  __shared__ __align__(16) unsigned short smem[BUF3];   // 144 KiB

  const int tid  = threadIdx.x;
  const int w    = tid >> 6;
  const int lane = tid & 63;
  const int l16  = lane & 15;
  const int quad = lane >> 4;
  const int wm   = (w & 3) * 64;
  const int wn   = (w >> 2) * 64;

  const int wg = blockIdx.x;
  const int sw = (wg & 7) * 32 + (wg >> 3);
  const int m0  = (sw & 15) * 256;
  const int rn0 = (sw >> 4) * 128;

  const int sr  = tid >> 3;
  const int scs = ((tid & 7) ^ (sr & 7)) * 8;
  const unsigned short* aBase = Ctx + (size_t)(m0 + sr) * HID + scs;
  const unsigned short* bBase = Wdb + (size_t)(rn0 + sr) * HID + scs;

#define STGA(UB, RB, KT)                                              \
  async16(aBase + (size_t)(RB) * HID + (KT),                          \
          (char*)smem + (UB) * 2 + (RB) * 128 + w * 1024)
#define STGB(UB, RB, KT)                                              \
  async16(bBase + (size_t)(RB) * HID + (KT),                          \
          (char*)smem + (UB) * 2 + 32768 + (RB) * 128 + w * 1024)

#define VM6  asm volatile("s_waitcnt vmcnt(6)" ::: "memory")
#define VM0  asm volatile("s_waitcnt vmcnt(0)" ::: "memory")

#define PHASE(UB, KK, STGBLK, WAITBLK)                                         \
  {                                                                            \
    const unsigned short* Ab = smem + (UB);                                    \
    const unsigned short* Bb = Ab + 16384;                                     \
    bf16x8 ta[4], tb[4];                                                       \
    ta[0] = frag(Ab, wm + l16, (KK) * 4 + quad);                               \
    _Pragma("unroll")                                                          \
    for (int j = 0; j < 4; ++j)  tb[j] = frag(Bb, wn + j * 16 + l16, (KK) * 4 + quad); \
    _Pragma("unroll")                                                          \
    for (int ii = 1; ii < 4; ++ii) ta[ii] = frag(Ab, wm + ii * 16 + l16, (KK) * 4 + quad); \
    STGBLK;                                                                    \
    __builtin_amdgcn_s_setprio(1);                                             \
    _Pragma("unroll")                                                          \
    for (int ii = 0; ii < 4; ++ii)                                             \
      _Pragma("unroll")                                                        \
      for (int j = 0; j < 4; ++j) mfma16(acc[ii][j], ta[ii], tb[j]);           \
    __builtin_amdgcn_s_setprio(0);                                             \
    asm volatile("s_waitcnt lgkmcnt(0)" ::: "memory");                         \
    WAITBLK;                                                                   \
    __builtin_amdgcn_s_barrier();                                              \
  }

  f32x4 acc[4][4];
  const f32x4 zero = {0.f, 0.f, 0.f, 0.f};
#pragma unroll
  for (int a = 0; a < 4; ++a)
#pragma unroll
    for (int j = 0; j < 4; ++j) acc[a][j] = zero;

  STGA(0, 0, 0);  STGA(0, 64, 0);  STGA(0, 128, 0);  STGA(0, 192, 0);
  STGB(0, 0, 0);  STGB(0, 64, 0);
  STGA(BUFU, 0, 64);  STGA(BUFU, 64, 64);  STGA(BUFU, 128, 64);  STGA(BUFU, 192, 64);
  STGB(BUFU, 0, 64);  STGB(BUFU, 64, 64);
  VM6;
  __builtin_amdgcn_s_barrier();

  int kb = 0;
  for (int g = 0; g < 5; ++g) {
    PHASE(0,        0, { STGA(2*BUFU, 0, kb+128); STGA(2*BUFU, 64, kb+128); STGA(2*BUFU, 128, kb+128); }, {});
    PHASE(0,        1, { STGA(2*BUFU, 192, kb+128); STGB(2*BUFU, 0, kb+128); STGB(2*BUFU, 64, kb+128); }, VM6);
    PHASE(BUFU,     0, { STGA(0, 0, kb+192); STGA(0, 64, kb+192); STGA(0, 128, kb+192); }, {});
    PHASE(BUFU,     1, { STGA(0, 192, kb+192); STGB(0, 0, kb+192); STGB(0, 64, kb+192); }, VM6);
    PHASE(2*BUFU,   0, { STGA(BUFU, 0, kb+256); STGA(BUFU, 64, kb+256); STGA(BUFU, 128, kb+256); }, {});
    PHASE(2*BUFU,   1, { STGA(BUFU, 192, kb+256); STGB(BUFU, 0, kb+256); STGB(BUFU, 64, kb+256); }, VM6);
    PHASE(0,        0, { STGA(2*BUFU, 0, kb+320); STGA(2*BUFU, 64, kb+320); STGA(2*BUFU, 128, kb+320); }, {});
    PHASE(0,        1, { STGA(2*BUFU, 192, kb+320); STGB(2*BUFU, 0, kb+320); STGB(2*BUFU, 64, kb+320); }, VM6);
    PHASE(BUFU,     0, { STGA(0, 0, kb+384); STGA(0, 64, kb+384); STGA(0, 128, kb+384); }, {});
    PHASE(BUFU,     1, { STGA(0, 192, kb+384); STGB(0, 0, kb+384); STGB(0, 64, kb+384); }, VM6);
    PHASE(2*BUFU,   0, { STGA(BUFU, 0, kb+448); STGA(BUFU, 64, kb+448); STGA(BUFU, 128, kb+448); }, {});
    PHASE(2*BUFU,   1, { STGA(BUFU, 192, kb+448); STGB(BUFU, 0, kb+448); STGB(BUFU, 64, kb+448); }, VM6);
    kb += 384;
  }

  PHASE(0,    0, {}, {});
  PHASE(0,    1, {}, VM0);
  PHASE(BUFU, 0, {}, {});
  PHASE(BUFU, 1, {}, {});

#pragma unroll
  for (int j = 0; j < 4; ++j) {
    int ng = rn0 + wn + j * 16 + l16;
    float bias = bd[ng];
#pragma unroll
    for (int a = 0; a < 4; ++a)
#pragma unroll
      for (int r = 0; r < 4; ++r) {
        int mg = m0 + wm + a * 16 + quad * 4 + r;
        size_t off = (size_t)mg * HID + ng;
        Out[off] = acc[a][j][r] + bias + Res[off];
      }
  }
#undef STGA
#undef STGB
#undef PHASE
#undef VM6
#undef VM0
}

// ---------------- V transpose: QKV V-part -> Vt[bh][d][s] ----------------
__global__ __launch_bounds__(256) void vtrans_kernel(const unsigned short* __restrict__ QKV,
                                                     unsigned short* __restrict__ Vt) {
  __shared__ __align__(16) unsigned short T[64][72];
  const int s0 = blockIdx.x * 64, d0 = blockIdx.y * 64, bh = blockIdx.z;
  const int b = bh >> 4, h = bh & 15;
  const int tid = threadIdx.x;
#pragma unroll
  for (int i = 0; i < 2; ++i) {
    int idx = i * 256 + tid;
    int r = idx >> 3, ch = idx & 7;
    const unsigned short* g = QKV + ((size_t)b * SEQ + s0 + r) * NQKV + 2 * HID + h * HD + d0 + ch * 8;
    *(uint4*)(&T[r][ch * 8]) = *(const uint4*)g;
  }
  __syncthreads();
#pragma unroll
  for (int i = 0; i < 2; ++i) {
    int idx = i * 256 + tid;
    int d = idx >> 3, ch = idx & 7;
    unsigned short v[8];
#pragma unroll
    for (int x = 0; x < 8; ++x) v[x] = T[ch * 8 + x][d];
    unsigned short* g = Vt + ((size_t)bh * HD + d0 + d) * SEQ + s0 + ch * 8;
    *(uint4*)g = *(const uint4*)v;
  }
}

// ---------------- flash attention: T14 pipeline + T12 in-register P (no Ps LDS) ----------------
// 1D grid 512, XCD-pinned: bid = (bh&7) + 8*(qb + 16*(bh>>3)) -> all 16 q-blocks of a
// bh share one XCD L2 (K/V fetched once per XCD). LDS: Ks 16K | Vts0 16K | Vts1 16K |
// Als 8K = 56KB -> 2 blocks/CU. Softmax P stays in registers: 16 cvt_pk + 8
// permlane32_swap build the PV A-fragments directly (h-half exchange), removing the
// Ps round-trip and its 4-way bank conflicts (6.3M/dispatch in R6).
__global__ __launch_bounds__(256, 2) void attn_kernel(
    const unsigned short* __restrict__ QKV, const unsigned short* __restrict__ Vt,
    const float* __restrict__ alibi, unsigned short* __restrict__ Ctx) {
  __shared__ __align__(16) char smem[57344];
  unsigned short* Ks   = (unsigned short*)smem;
  unsigned short* Vts0 = (unsigned short*)(smem + 16384);
  unsigned short* Vts1 = (unsigned short*)(smem + 32768);
  float*          Alsf = (float*)(smem + 49152);
  unsigned short* Qs   = (unsigned short*)smem;   // alias: Q staging (32 KB over Ks+Vts0)

  const int tid = threadIdx.x, w = tid >> 6, lane = tid & 63;
  const int l32 = lane & 31, h = lane >> 5;
  // XCD-pinned decode
  const int bid = blockIdx.x;
  const int t  = bid >> 3;
  const int q0 = (t & 15) * 128;
  const int bh = (bid & 7) + 8 * (t >> 4);
  const int b = bh >> 4, hh = bh & 15;
  const size_t rowbase = (size_t)b * SEQ;
  const float* ali = alibi + (size_t)bh * SEQ;
  const unsigned short* Vbh = Vt + (size_t)bh * HD * SEQ;

  // ---- stage Q (aliases Ks+Vts0) + alibi row (8KB) ----
  {
    const unsigned short* qbase = QKV + (rowbase + q0) * NQKV + hh * HD;
#pragma unroll
    for (int i = 0; i < 8; ++i) {
      int slot = i * 256 + w * 64 + lane;
      int r = slot >> 4, c = (slot & 15) ^ (r & 15);
      async16(qbase + (size_t)r * NQKV + c * 8, (char*)Qs + (size_t)(i * 256 + w * 64) * 16);
    }
    const char* asrc = (const char*)ali;
#pragma unroll
    for (int i = 0; i < 2; ++i) {
      int slot = i * 256 + w * 64 + lane;
      async16(asrc + (size_t)slot * 16, (char*)Alsf + (size_t)(i * 256 + w * 64) * 16);
    }
  }
  __syncthreads();
  bf16x8 qf[8];
  {
    int qr = w * 32 + l32;
#pragma unroll
    for (int ks = 0; ks < 8; ++ks) {
      int c = (ks * 2 + h) ^ (qr & 15);
      qf[ks] = *(const bf16x8*)(Qs + (qr * 16 + c) * 8);
    }
  }

  f32x16 oacc[4];
  float l_acc = 0.f;
#pragma unroll
  for (int nb = 0; nb < 4; ++nb)
#pragma unroll
    for (int r = 0; r < 16; ++r) oacc[nb][r] = 0.f;

  __syncthreads();   // qf reads complete before K0 staging overwrites alias

  // ---- stage K(0) -> Ks, V(0) -> Vts0 ----
  {
    const unsigned short* kbase = QKV + rowbase * NQKV + HID + hh * HD;
#pragma unroll
    for (int i = 0; i < 4; ++i) {
      int slot = i * 256 + w * 64 + lane;
      int r = slot >> 4, c = (slot & 15) ^ (r & 15);
      async16(kbase + (size_t)r * NQKV + c * 8, (char*)Ks + (size_t)(i * 256 + w * 64) * 16);
    }
#pragma unroll
    for (int i = 0; i < 4; ++i) {
      int slot = i * 256 + w * 64 + lane;
      int r = slot >> 3, c = (slot & 7) ^ (r & 7);
      async16(Vbh + (size_t)r * SEQ + c * 8, (char*)Vts0 + (size_t)(i * 256 + w * 64) * 16);
    }
  }
  __syncthreads();

  for (int kt = 0; kt < SEQ / 64; ++kt) {
    // ---- S^T = K Q^T on current K tile ----
    f32x16 sacc[2];
#pragma unroll
    for (int mb = 0; mb < 2; ++mb)
#pragma unroll
      for (int r = 0; r < 16; ++r) sacc[mb][r] = 0.f;
    __builtin_amdgcn_s_setprio(1);
#pragma unroll
    for (int ks = 0; ks < 8; ++ks) {
#pragma unroll
      for (int mb = 0; mb < 2; ++mb) {
        bf16x8 kf = *(const bf16x8*)(Ks + ((mb * 32 + l32) * 16 + ((ks * 2 + h) ^ (l32 & 15))) * 8);
        sacc[mb] = __builtin_amdgcn_mfma_f32_32x32x16_bf16(kf, qf[ks], sacc[mb], 0, 0, 0);
      }
    }
    __builtin_amdgcn_s_setprio(0);
    asm volatile("s_waitcnt lgkmcnt(0)" ::: "memory");
    __builtin_amdgcn_s_barrier();            // all K-reads done -> Ks free

    // ---- issue K(t+1) -> Ks, V(t+1) -> Vts[(t+1)&1] (drain at iter end) ----
    if (kt + 1 < SEQ / 64) {
      const unsigned short* kbase = QKV + (rowbase + (kt + 1) * 64) * NQKV + HID + hh * HD;
#pragma unroll
      for (int i = 0; i < 4; ++i) {
        int slot = i * 256 + w * 64 + lane;
        int r = slot >> 4, c = (slot & 15) ^ (r & 15);
        async16(kbase + (size_t)r * NQKV + c * 8, (char*)Ks + (size_t)(i * 256 + w * 64) * 16);
      }
      const unsigned short* vbase = Vbh + (kt + 1) * 64;
      unsigned short* vdst = ((kt + 1) & 1) ? Vts1 : Vts0;
#pragma unroll
      for (int i = 0; i < 4; ++i) {
        int slot = i * 256 + w * 64 + lane;
        int r = slot >> 3, c = (slot & 7) ^ (r & 7);
        async16(vbase + (size_t)r * SEQ + c * 8, (char*)vdst + (size_t)(i * 256 + w * 64) * 16);
      }
    }

    // ---- softmax + in-register P pack (T12) ----
    // lane (q=w*32+l32, h) holds sacc[mb][r] = S[key = mb*32 + (r&3) + 8*(r>>2) + 4h][q].
    // Pack pairs, then permlane32_swap (vdst-upper <-> vsrc-lower) exchanges h-halves:
    // swap(cLow, cHigh) yields (d0, d2) of the PV A-fragment for both h's.
    const float* alsk = Alsf + kt * 64 + 4 * h;
    bf16x8 pfr[4];
#pragma unroll
    for (int mb = 0; mb < 2; ++mb) {
      float p[16];
#pragma unroll
      for (int g = 0; g < 4; ++g) {
        float4 av = *(const float4*)(alsk + mb * 32 + g * 8);
        p[g * 4 + 0] = __builtin_amdgcn_exp2f(sacc[mb][g * 4 + 0] * SCALE_L2 + av.x * LOG2E);
        p[g * 4 + 1] = __builtin_amdgcn_exp2f(sacc[mb][g * 4 + 1] * SCALE_L2 + av.y * LOG2E);
        p[g * 4 + 2] = __builtin_amdgcn_exp2f(sacc[mb][g * 4 + 2] * SCALE_L2 + av.z * LOG2E);
        p[g * 4 + 3] = __builtin_amdgcn_exp2f(sacc[mb][g * 4 + 3] * SCALE_L2 + av.w * LOG2E);
        l_acc += (p[g * 4 + 0] + p[g * 4 + 1]) + (p[g * 4 + 2] + p[g * 4 + 3]);
      }
      unsigned c0 = pkbf(p[0],  p[1]),  c1 = pkbf(p[2],  p[3]);    // keys 4h+{0,1},{2,3}
      unsigned c2 = pkbf(p[4],  p[5]),  c3 = pkbf(p[6],  p[7]);    // keys 8+4h+...
      unsigned c4 = pkbf(p[8],  p[9]),  c5 = pkbf(p[10], p[11]);   // keys 16+4h+...
      unsigned c6 = pkbf(p[12], p[13]), c7 = pkbf(p[14], p[15]);   // keys 24+4h+...
      pl32swap(c0, c2);  pl32swap(c1, c3);   // frag half0 dwords: c0=d0 c1=d1 c2=d2 c3=d3
      pl32swap(c4, c6);  pl32swap(c5, c7);   // frag half1
      uint4 f0; f0.x = c0; f0.y = c1; f0.z = c2; f0.w = c3;
      uint4 f1; f1.x = c4; f1.y = c5; f1.z = c6; f1.w = c7;
      pfr[mb * 2 + 0] = __builtin_bit_cast(bf16x8, f0);
      pfr[mb * 2 + 1] = __builtin_bit_cast(bf16x8, f1);
    }

    // ---- O += P V on V(t) ----
    const unsigned short* vcur = (kt & 1) ? Vts1 : Vts0;
    __builtin_amdgcn_s_setprio(1);
#pragma unroll
    for (int ks2 = 0; ks2 < 4; ++ks2) {
      bf16x8 pf = pfr[ks2];
#pragma unroll
      for (int nb = 0; nb < 4; ++nb) {
        bf16x8 vf = *(const bf16x8*)(vcur + ((nb * 32 + l32) * 8 + ((ks2 * 2 + h) ^ (l32 & 7))) * 8);
        oacc[nb] = __builtin_amdgcn_mfma_f32_32x32x16_bf16(pf, vf, oacc[nb], 0, 0, 0);
      }
    }
    __builtin_amdgcn_s_setprio(0);

    asm volatile("s_waitcnt lgkmcnt(0) vmcnt(0)" ::: "memory");
    __builtin_amdgcn_s_barrier();            // K(t+1)/V(t+1) visible
  }

  float lf = l_acc + __shfl_xor(l_acc, 32, 64);
  float rinv[16];
#pragma unroll
  for (int reg = 0; reg < 16; ++reg) {
    int row = (reg & 3) + 8 * (reg >> 2) + 4 * h;
    rinv[reg] = 1.0f / __shfl(lf, row, 64);
  }

#pragma unroll
  for (int nb = 0; nb < 4; ++nb)
#pragma unroll
    for (int reg = 0; reg < 16; ++reg) {
      int row = (reg & 3) + 8 * (reg >> 2) + 4 * h;
      size_t qg = rowbase + q0 + w * 32 + row;
      Ctx[qg * HID + hh * HD + nb * 32 + l32] = f2bf(oacc[nb][reg] * rinv[reg]);
    }
}

// ---------------- launch ----------------
extern "C" void kernel_launch(void* const* d_in, const int* in_sizes, int n_in,
                              void* d_out, int out_size, void* d_ws, size_t ws_size,
                              hipStream_t stream) {
  const float* hidden   = (const float*)d_in[0];
  const float* residual = (const float*)d_in[1];
  const float* alibi    = (const float*)d_in[2];
  const float* Wq = (const float*)d_in[3];
  const float* bq = (const float*)d_in[4];
  const float* Wk = (const float*)d_in[5];
  const float* bk = (const float*)d_in[6];
  const float* Wv = (const float*)d_in[7];
  const float* bv = (const float*)d_in[8];
  const float* Wd = (const float*)d_in[9];
  const float* bd = (const float*)d_in[10];
  float* out = (float*)d_out;

  unsigned short* Xb    = (unsigned short*)d_ws;                    // 4096*2048
  unsigned short* Wqkvb = Xb + (size_t)MROWS * HID;                 // 6144*2048
  unsigned short* Wdb   = Wqkvb + (size_t)NQKV * HID;               // 2048*2048
  unsigned short* QKVb  = Wdb + (size_t)HID * HID;                  // 4096*6144
  unsigned short* Ctxb  = QKVb + (size_t)MROWS * NQKV;              // 4096*2048
  unsigned short* Vtb   = Wqkvb;  // Vt reuses Wqkvb region (dead after gemm_qkv)

  const int nX = MROWS * HID, nW = HID * HID;
  cvt_kernel<<<nX / 4 / 256, 256, 0, stream>>>(hidden, Xb, nX);
  cvtw_kernel<<<dim3(nW / 4 / 256, 4), 256, 0, stream>>>(Wq, Wk, Wv, Wd, Wqkvb);

  gemm_qkv384_kernel<<<256, 512, 0, stream>>>(Xb, Wqkvb, bq, bk, bv, QKVb);
  vtrans_kernel<<<dim3(SEQ / 64, HD / 64, BATCH * NHEAD), 256, 0, stream>>>(QKVb, Vtb);
  attn_kernel<<<512, 256, 0, stream>>>(QKVb, Vtb, alibi, Ctxb);
  gemm_out384_kernel<<<256, 512, 0, stream>>>(Ctxb, Wdb, bd, residual, out);
}

// Round 8
// 433.874 us; speedup vs baseline: 1.0235x; 1.0119x over previous
//
#include <hip/hip_runtime.h>

// ---------------- problem constants ----------------
#define HID   2048
#define NHEAD 16
#define HD    128
#define SEQ   2048
#define BATCH 2
#define MROWS (BATCH*SEQ)        // 4096
#define NQKV  (3*HID)            // 6144
#define INV_NORM 0.08838834764831845f
#define LOG2E    1.4426950408889634f
#define SCALE_L2 (INV_NORM*LOG2E)

typedef __attribute__((ext_vector_type(8)))  __bf16 bf16x8;
typedef __attribute__((ext_vector_type(4)))  float  f32x4;
typedef __attribute__((ext_vector_type(16))) float  f32x16;

typedef __attribute__((address_space(1))) void GV;
typedef __attribute__((address_space(3))) void LV;

__device__ __forceinline__ void async16(const void* g, void* l) {
  __builtin_amdgcn_global_load_lds((const GV*)g, (LV*)l, 16, 0, 0);
}

__device__ __forceinline__ unsigned short f2bf(float f) {
  unsigned u = __builtin_bit_cast(unsigned, f);
  u += 0x7FFFu + ((u >> 16) & 1u);       // RNE
  return (unsigned short)(u >> 16);
}

__device__ __forceinline__ unsigned pkbf(float a, float b) {
#if __has_builtin(__builtin_amdgcn_cvt_pk_bf16_f32)
  typedef __attribute__((ext_vector_type(2))) __bf16 bf16x2;
  bf16x2 r = __builtin_amdgcn_cvt_pk_bf16_f32(a, b);
  return __builtin_bit_cast(unsigned, r);
#else
  return (unsigned)f2bf(a) | ((unsigned)f2bf(b) << 16);
#endif
}

// exchange a's upper 32 lanes with b's lower 32 lanes (v_permlane32_swap_b32 a, b)
__device__ __forceinline__ void pl32swap(unsigned &a, unsigned &b) {
#if __has_builtin(__builtin_amdgcn_permlane32_swap)
  typedef __attribute__((ext_vector_type(2))) unsigned u32x2;
  u32x2 r = __builtin_amdgcn_permlane32_swap(a, b, false, false);
  a = r[0]; b = r[1];
#else
  asm volatile("v_permlane32_swap_b32 %0, %1" : "+v"(a), "+v"(b));
#endif
}

__device__ __forceinline__ void mfma16(f32x4& c, bf16x8 a, bf16x8 b) {
  c = __builtin_amdgcn_mfma_f32_16x16x32_bf16(a, b, c, 0, 0, 0);
}

// LDS fragment read with chunk-XOR swizzle (BK=64 -> 8 chunks of 16B per row)
__device__ __forceinline__ bf16x8 frag(const unsigned short* buf, int row, int chunk) {
  return *(const bf16x8*)(buf + ((row * 8 + (chunk ^ (row & 7))) << 3));
}

// ---------------- fp32 -> bf16 cast, all tensors in one launch ----------------
// y=0: hidden (MROWS*HID); y=1..4: Wq,Wk,Wv,Wd (HID*HID each), laid out consecutively
// after Xb in the workspace. Over-provisioned x-blocks early-exit.
__global__ __launch_bounds__(256) void cvt_all_kernel(
    const float* __restrict__ hidden,
    const float* __restrict__ W0, const float* __restrict__ W1,
    const float* __restrict__ W2, const float* __restrict__ W3,
    unsigned short* __restrict__ Xb) {
  const int sel = blockIdx.y;
  const float* src;
  unsigned short* dst;
  int n;
  if (sel == 0) { src = hidden; dst = Xb; n = MROWS * HID; }
  else {
    src = (sel == 1) ? W0 : (sel == 2) ? W1 : (sel == 3) ? W2 : W3;
    dst = Xb + (size_t)MROWS * HID + (size_t)(sel - 1) * HID * HID;
    n = HID * HID;
  }
  int i = (blockIdx.x * 256 + threadIdx.x) * 4;
  if (i >= n) return;
  float4 v = *(const float4*)(src + i);
  ushort4 o;
  o.x = f2bf(v.x); o.y = f2bf(v.y); o.z = f2bf(v.z); o.w = f2bf(v.w);
  *(ushort4*)(dst + i) = o;
}

// ---------------- GEMM 1: QKV projection, persistent 256-block, 3x(256x128) passes ----
// (R5 structure, unchanged: static buffer rotation, 1 barrier/phase, vmcnt(6) FIFO)
#define BUFU (24576)   // ushorts per buffer (48KB): A 16384 + B 8192
#define BUF3 (3 * BUFU)

__global__ __launch_bounds__(512, 2) void gemm_qkv384_kernel(
    const unsigned short* __restrict__ Xb, const unsigned short* __restrict__ Wb,
    const float* __restrict__ bq, const float* __restrict__ bk,
    const float* __restrict__ bv, unsigned short* __restrict__ Cout) {
  __shared__ __align__(16) unsigned short smem[BUF3];   // 144 KiB

  const int tid  = threadIdx.x;
  const int w    = tid >> 6;
  const int lane = tid & 63;
  const int l16  = lane & 15;
  const int quad = lane >> 4;
  const int wm   = (w & 3) * 64;    // 4 M-waves
  const int wn   = (w >> 2) * 64;   // 2 N-waves

  const int wg = blockIdx.x;
  const int sw = (wg & 7) * 32 + (wg >> 3);
  const int m0  = (sw & 15) * 256;
  const int rn0 = (sw >> 4) * 384;

  const int sr  = tid >> 3;
  const int scs = ((tid & 7) ^ (sr & 7)) * 8;
  const unsigned short* aBase = Xb + (size_t)(m0 + sr) * HID + scs;

#define STGA(UB, RB, KT)                                              \
  async16(aBase + (size_t)(RB) * HID + (KT),                          \
          (char*)smem + (UB) * 2 + (RB) * 128 + w * 1024)
#define STGB(UB, RB, KT)                                              \
  async16(bBase + (size_t)(RB) * HID + (KT),                          \
          (char*)smem + (UB) * 2 + 32768 + (RB) * 128 + w * 1024)

#define VM6  asm volatile("s_waitcnt vmcnt(6)" ::: "memory")
#define VM0  asm volatile("s_waitcnt vmcnt(0)" ::: "memory")

#define PHASE(UB, KK, STGBLK, WAITBLK)                                         \
  {                                                                            \
    const unsigned short* Ab = smem + (UB);                                    \
    const unsigned short* Bb = Ab + 16384;                                     \
    bf16x8 ta[4], tb[4];                                                       \
    ta[0] = frag(Ab, wm + l16, (KK) * 4 + quad);                               \
    _Pragma("unroll")                                                          \
    for (int j = 0; j < 4; ++j)  tb[j] = frag(Bb, wn + j * 16 + l16, (KK) * 4 + quad); \
    _Pragma("unroll")                                                          \
    for (int ii = 1; ii < 4; ++ii) ta[ii] = frag(Ab, wm + ii * 16 + l16, (KK) * 4 + quad); \
    STGBLK;                                                                    \
    __builtin_amdgcn_s_setprio(1);                                             \
    _Pragma("unroll")                                                          \
    for (int ii = 0; ii < 4; ++ii)                                             \
      _Pragma("unroll")                                                        \
      for (int j = 0; j < 4; ++j) mfma16(acc[ii][j], ta[ii], tb[j]);           \
    __builtin_amdgcn_s_setprio(0);                                             \
    asm volatile("s_waitcnt lgkmcnt(0)" ::: "memory");                         \
    WAITBLK;                                                                   \
    __builtin_amdgcn_s_barrier();                                              \
  }

  for (int p = 0; p < 3; ++p) {
    const unsigned short* bBase = Wb + (size_t)(rn0 + p * 128 + sr) * HID + scs;

    f32x4 acc[4][4];
    const f32x4 zero = {0.f, 0.f, 0.f, 0.f};
#pragma unroll
    for (int a = 0; a < 4; ++a)
#pragma unroll
      for (int j = 0; j < 4; ++j) acc[a][j] = zero;

    STGA(0, 0, 0);  STGA(0, 64, 0);  STGA(0, 128, 0);  STGA(0, 192, 0);
    STGB(0, 0, 0);  STGB(0, 64, 0);
    STGA(BUFU, 0, 64);  STGA(BUFU, 64, 64);  STGA(BUFU, 128, 64);  STGA(BUFU, 192, 64);
    STGB(BUFU, 0, 64);  STGB(BUFU, 64, 64);
    VM6;
    __builtin_amdgcn_s_barrier();

    int kb = 0;
    for (int g = 0; g < 5; ++g) {
      PHASE(0,        0, { STGA(2*BUFU, 0, kb+128); STGA(2*BUFU, 64, kb+128); STGA(2*BUFU, 128, kb+128); }, {});
      PHASE(0,        1, { STGA(2*BUFU, 192, kb+128); STGB(2*BUFU, 0, kb+128); STGB(2*BUFU, 64, kb+128); }, VM6);
      PHASE(BUFU,     0, { STGA(0, 0, kb+192); STGA(0, 64, kb+192); STGA(0, 128, kb+192); }, {});
      PHASE(BUFU,     1, { STGA(0, 192, kb+192); STGB(0, 0, kb+192); STGB(0, 64, kb+192); }, VM6);
      PHASE(2*BUFU,   0, { STGA(BUFU, 0, kb+256); STGA(BUFU, 64, kb+256); STGA(BUFU, 128, kb+256); }, {});
      PHASE(2*BUFU,   1, { STGA(BUFU, 192, kb+256); STGB(BUFU, 0, kb+256); STGB(BUFU, 64, kb+256); }, VM6);
      PHASE(0,        0, { STGA(2*BUFU, 0, kb+320); STGA(2*BUFU, 64, kb+320); STGA(2*BUFU, 128, kb+320); }, {});
      PHASE(0,        1, { STGA(2*BUFU, 192, kb+320); STGB(2*BUFU, 0, kb+320); STGB(2*BUFU, 64, kb+320); }, VM6);
      PHASE(BUFU,     0, { STGA(0, 0, kb+384); STGA(0, 64, kb+384); STGA(0, 128, kb+384); }, {});
      PHASE(BUFU,     1, { STGA(0, 192, kb+384); STGB(0, 0, kb+384); STGB(0, 64, kb+384); }, VM6);
      PHASE(2*BUFU,   0, { STGA(BUFU, 0, kb+448); STGA(BUFU, 64, kb+448); STGA(BUFU, 128, kb+448); }, {});
      PHASE(2*BUFU,   1, { STGA(BUFU, 192, kb+448); STGB(BUFU, 0, kb+448); STGB(BUFU, 64, kb+448); }, VM6);
      kb += 384;
    }

    PHASE(0,    0, {}, {});
    PHASE(0,    1, {}, VM0);
    PHASE(BUFU, 0, {}, {});
    PHASE(BUFU, 1, {}, {});

#pragma unroll
    for (int j = 0; j < 4; ++j) {
      int ng = rn0 + p * 128 + wn + j * 16 + l16;
      float bias = (ng < HID) ? bq[ng] : (ng < 2 * HID ? bk[ng - HID] : bv[ng - 2 * HID]);
#pragma unroll
      for (int a = 0; a < 4; ++a)
#pragma unroll
        for (int r = 0; r < 4; ++r) {
          int mg = m0 + wm + a * 16 + quad * 4 + r;
          Cout[(size_t)mg * NQKV + ng] = f2bf(acc[a][j][r] + bias);
        }
    }
  }
#undef STGA
#undef STGB
#undef PHASE
#undef VM6
#undef VM0
}

// ---------------- GEMM 2: out-proj, SAME persistent structure (single pass) ----------------
__global__ __launch_bounds__(512, 2) void gemm_out384_kernel(
    const unsigned short* __restrict__ Ctx, const unsigned short* __restrict__ Wdb,
    const float* __restrict__ bd, const float* __restrict__ Res,
    float* __restrict__ Out) {
  __shared__ __align__(16) unsigned short smem[BUF3];   // 144 KiB

  const int tid  = threadIdx.x;
  const int w    = tid >> 6;
  const int lane = tid & 63;
  const int l16  = lane & 15;
  const int quad = lane >> 4;
  const int wm   = (w & 3) * 64;
  const int wn   = (w >> 2) * 64;

  const int wg = blockIdx.x;
  const int sw = (wg & 7) * 32 + (wg >> 3);
  const int m0  = (sw & 15) * 256;
  const int rn0 = (sw >> 4) * 128;

  const int sr  = tid >> 3;
  const int scs = ((tid & 7) ^ (sr & 7)) * 8;
  const unsigned short* aBase = Ctx + (size_t)(m0 + sr) * HID + scs;
  const unsigned short* bBase = Wdb + (size_t)(rn0 + sr) * HID + scs;

#define STGA(UB, RB, KT)                                              \
  async16(aBase + (size_t)(RB) * HID + (KT),                          \
          (char*)smem + (UB) * 2 + (RB) * 128 + w * 1024)
#define STGB(UB, RB, KT)                                              \
  async16(bBase + (size_t)(RB) * HID + (KT),                          \
          (char*)smem + (UB) * 2 + 32768 + (RB) * 128 + w * 1024)

#define VM6  asm volatile("s_waitcnt vmcnt(6)" ::: "memory")
#define VM0  asm volatile("s_waitcnt vmcnt(0)" ::: "memory")

#define PHASE(UB, KK, STGBLK, WAITBLK)                                         \
  {                                                                            \
    const unsigned short* Ab = smem + (UB);                                    \
    const unsigned short* Bb = Ab + 16384;                                     \
    bf16x8 ta[4], tb[4];                                                       \
    ta[0] = frag(Ab, wm + l16, (KK) * 4 + quad);                               \
    _Pragma("unroll")                                                          \
    for (int j = 0; j < 4; ++j)  tb[j] = frag(Bb, wn + j * 16 + l16, (KK) * 4 + quad); \
    _Pragma("unroll")                                                          \
    for (int ii = 1; ii < 4; ++ii) ta[ii] = frag(Ab, wm + ii * 16 + l16, (KK) * 4 + quad); \
    STGBLK;                                                                    \
    __builtin_amdgcn_s_setprio(1);                                             \
    _Pragma("unroll")                                                          \
    for (int ii = 0; ii < 4; ++ii)                                             \
      _Pragma("unroll")                                                        \
      for (int j = 0; j < 4; ++j) mfma16(acc[ii][j], ta[ii], tb[j]);           \
    __builtin_amdgcn_s_setprio(0);                                             \
    asm volatile("s_waitcnt lgkmcnt(0)" ::: "memory");                         \
    WAITBLK;                                                                   \
    __builtin_amdgcn_s_barrier();                                              \
  }

  f32x4 acc[4][4];
  const f32x4 zero = {0.f, 0.f, 0.f, 0.f};
#pragma unroll
  for (int a = 0; a < 4; ++a)
#pragma unroll
    for (int j = 0; j < 4; ++j) acc[a][j] = zero;

  STGA(0, 0, 0);  STGA(0, 64, 0);  STGA(0, 128, 0);  STGA(0, 192, 0);
  STGB(0, 0, 0);  STGB(0, 64, 0);
  STGA(BUFU, 0, 64);  STGA(BUFU, 64, 64);  STGA(BUFU, 128, 64);  STGA(BUFU, 192, 64);
  STGB(BUFU, 0, 64);  STGB(BUFU, 64, 64);
  VM6;
  __builtin_amdgcn_s_barrier();

  int kb = 0;
  for (int g = 0; g < 5; ++g) {
    PHASE(0,        0, { STGA(2*BUFU, 0, kb+128); STGA(2*BUFU, 64, kb+128); STGA(2*BUFU, 128, kb+128); }, {});
    PHASE(0,        1, { STGA(2*BUFU, 192, kb+128); STGB(2*BUFU, 0, kb+128); STGB(2*BUFU, 64, kb+128); }, VM6);
    PHASE(BUFU,     0, { STGA(0, 0, kb+192); STGA(0, 64, kb+192); STGA(0, 128, kb+192); }, {});
    PHASE(BUFU,     1, { STGA(0, 192, kb+192); STGB(0, 0, kb+192); STGB(0, 64, kb+192); }, VM6);
    PHASE(2*BUFU,   0, { STGA(BUFU, 0, kb+256); STGA(BUFU, 64, kb+256); STGA(BUFU, 128, kb+256); }, {});
    PHASE(2*BUFU,   1, { STGA(BUFU, 192, kb+256); STGB(BUFU, 0, kb+256); STGB(BUFU, 64, kb+256); }, VM6);
    PHASE(0,        0, { STGA(2*BUFU, 0, kb+320); STGA(2*BUFU, 64, kb+320); STGA(2*BUFU, 128, kb+320); }, {});
    PHASE(0,        1, { STGA(2*BUFU, 192, kb+320); STGB(2*BUFU, 0, kb+320); STGB(2*BUFU, 64, kb+320); }, VM6);
    PHASE(BUFU,     0, { STGA(0, 0, kb+384); STGA(0, 64, kb+384); STGA(0, 128, kb+384); }, {});
    PHASE(BUFU,     1, { STGA(0, 192, kb+384); STGB(0, 0, kb+384); STGB(0, 64, kb+384); }, VM6);
    PHASE(2*BUFU,   0, { STGA(BUFU, 0, kb+448); STGA(BUFU, 64, kb+448); STGA(BUFU, 128, kb+448); }, {});
    PHASE(2*BUFU,   1, { STGA(BUFU, 192, kb+448); STGB(BUFU, 0, kb+448); STGB(BUFU, 64, kb+448); }, VM6);
    kb += 384;
  }

  PHASE(0,    0, {}, {});
  PHASE(0,    1, {}, VM0);
  PHASE(BUFU, 0, {}, {});
  PHASE(BUFU, 1, {}, {});

#pragma unroll
  for (int j = 0; j < 4; ++j) {
    int ng = rn0 + wn + j * 16 + l16;
    float bias = bd[ng];
#pragma unroll
    for (int a = 0; a < 4; ++a)
#pragma unroll
      for (int r = 0; r < 4; ++r) {
        int mg = m0 + wm + a * 16 + quad * 4 + r;
        size_t off = (size_t)mg * HID + ng;
        Out[off] = acc[a][j][r] + bias + Res[off];
      }
  }
#undef STGA
#undef STGB
#undef PHASE
#undef VM6
#undef VM0
}

// ---------------- V transpose: QKV V-part -> Vt[bh][d][s] ----------------
__global__ __launch_bounds__(256) void vtrans_kernel(const unsigned short* __restrict__ QKV,
                                                     unsigned short* __restrict__ Vt) {
  __shared__ __align__(16) unsigned short T[64][72];
  const int s0 = blockIdx.x * 64, d0 = blockIdx.y * 64, bh = blockIdx.z;
  const int b = bh >> 4, h = bh & 15;
  const int tid = threadIdx.x;
#pragma unroll
  for (int i = 0; i < 2; ++i) {
    int idx = i * 256 + tid;
    int r = idx >> 3, ch = idx & 7;
    const unsigned short* g = QKV + ((size_t)b * SEQ + s0 + r) * NQKV + 2 * HID + h * HD + d0 + ch * 8;
    *(uint4*)(&T[r][ch * 8]) = *(const uint4*)g;
  }
  __syncthreads();
#pragma unroll
  for (int i = 0; i < 2; ++i) {
    int idx = i * 256 + tid;
    int d = idx >> 3, ch = idx & 7;
    unsigned short v[8];
#pragma unroll
    for (int x = 0; x < 8; ++x) v[x] = T[ch * 8 + x][d];
    unsigned short* g = Vt + ((size_t)bh * HD + d0 + d) * SEQ + s0 + ch * 8;
    *(uint4*)g = *(const uint4*)v;
  }
}

// ---------------- flash attention: full-iteration prefetch, 1 barrier/iter ----------------
// XCD-pinned 1D grid 512. LDS: Ks0/Ks1 16K each | Vts0/Vts1 16K each | Als 8K = 72KB
// -> 2 blocks/CU. Schedule per iter t:
//   QK^T(K[t&1]) -> softmax in-reg (T12) -> PV(V[t&1])
//   -> lgkm(0) [WAR] -> vmcnt(0) [drains K/V(t+1), issued ONE FULL ITER ago] -> barrier
//   -> issue K/V(t+2) into buf[t&1] (dead: all waves past their reads at the barrier).
// Waited loads have QK^T+softmax+PV (~full iter) of latency coverage; single barrier.
__global__ __launch_bounds__(256, 2) void attn_kernel(
    const unsigned short* __restrict__ QKV, const unsigned short* __restrict__ Vt,
    const float* __restrict__ alibi, unsigned short* __restrict__ Ctx) {
  __shared__ __align__(16) char smem[73728];
  unsigned short* Ks0  = (unsigned short*)smem;
  unsigned short* Ks1  = (unsigned short*)(smem + 16384);
  unsigned short* Vts0 = (unsigned short*)(smem + 32768);
  unsigned short* Vts1 = (unsigned short*)(smem + 49152);
  float*          Alsf = (float*)(smem + 65536);
  unsigned short* Qs   = (unsigned short*)smem;   // alias: Q staging (32 KB over Ks0+Ks1)

  const int tid = threadIdx.x, w = tid >> 6, lane = tid & 63;
  const int l32 = lane & 31, h = lane >> 5;
  // XCD-pinned decode: all 16 q-blocks of one bh share an XCD
  const int bid = blockIdx.x;
  const int t  = bid >> 3;
  const int q0 = (t & 15) * 128;
  const int bh = (bid & 7) + 8 * (t >> 4);
  const int b = bh >> 4, hh = bh & 15;
  const size_t rowbase = (size_t)b * SEQ;
  const float* ali = alibi + (size_t)bh * SEQ;
  const unsigned short* Vbh = Vt + (size_t)bh * HD * SEQ;

  // ---- stage Q (aliases Ks0+Ks1) + alibi row (8KB) ----
  {
    const unsigned short* qbase = QKV + (rowbase + q0) * NQKV + hh * HD;
#pragma unroll
    for (int i = 0; i < 8; ++i) {
      int slot = i * 256 + w * 64 + lane;
      int r = slot >> 4, c = (slot & 15) ^ (r & 15);
      async16(qbase + (size_t)r * NQKV + c * 8, (char*)Qs + (size_t)(i * 256 + w * 64) * 16);
    }
    const char* asrc = (const char*)ali;
#pragma unroll
    for (int i = 0; i < 2; ++i) {
      int slot = i * 256 + w * 64 + lane;
      async16(asrc + (size_t)slot * 16, (char*)Alsf + (size_t)(i * 256 + w * 64) * 16);
    }
  }
  __syncthreads();
  bf16x8 qf[8];
  {
    int qr = w * 32 + l32;
#pragma unroll
    for (int ks = 0; ks < 8; ++ks) {
      int c = (ks * 2 + h) ^ (qr & 15);
      qf[ks] = *(const bf16x8*)(Qs + (qr * 16 + c) * 8);
    }
  }

  f32x16 oacc[4];
  float l_acc = 0.f;
#pragma unroll
  for (int nb = 0; nb < 4; ++nb)
#pragma unroll
    for (int r = 0; r < 16; ++r) oacc[nb][r] = 0.f;

  __syncthreads();   // qf reads complete before K staging overwrites alias

// stage K(T)->KD, V(T)->VD (per-wave: 4+4 async16)
#define STAGE_KV(T, KD, VD)                                                      \
  {                                                                              \
    const unsigned short* kbase = QKV + (rowbase + (T) * 64) * NQKV + HID + hh * HD; \
    _Pragma("unroll")                                                            \
    for (int i = 0; i < 4; ++i) {                                                \
      int slot = i * 256 + w * 64 + lane;                                        \
      int r = slot >> 4, c = (slot & 15) ^ (r & 15);                             \
      async16(kbase + (size_t)r * NQKV + c * 8, (char*)(KD) + (size_t)(i * 256 + w * 64) * 16); \
    }                                                                            \
    const unsigned short* vbase = Vbh + (T) * 64;                                \
    _Pragma("unroll")                                                            \
    for (int i = 0; i < 4; ++i) {                                                \
      int slot = i * 256 + w * 64 + lane;                                        \
      int r = slot >> 3, c = (slot & 7) ^ (r & 7);                               \
      async16(vbase + (size_t)r * SEQ + c * 8, (char*)(VD) + (size_t)(i * 256 + w * 64) * 16); \
    }                                                                            \
  }

  // prologue: tiles 0 and 1; drain tile 0, leave tile 1 in flight
  STAGE_KV(0, Ks0, Vts0);
  STAGE_KV(1, Ks1, Vts1);
  asm volatile("s_waitcnt vmcnt(8)" ::: "memory");
  __builtin_amdgcn_s_barrier();

  for (int kt = 0; kt < SEQ / 64; ++kt) {
    const unsigned short* Kc = (kt & 1) ? Ks1 : Ks0;
    const unsigned short* Vc = (kt & 1) ? Vts1 : Vts0;

    // ---- S^T = K Q^T ----
    f32x16 sacc[2];
#pragma unroll
    for (int mb = 0; mb < 2; ++mb)
#pragma unroll
      for (int r = 0; r < 16; ++r) sacc[mb][r] = 0.f;
    __builtin_amdgcn_s_setprio(1);
#pragma unroll
    for (int ks = 0; ks < 8; ++ks) {
#pragma unroll
      for (int mb = 0; mb < 2; ++mb) {
        bf16x8 kf = *(const bf16x8*)(Kc + ((mb * 32 + l32) * 16 + ((ks * 2 + h) ^ (l32 & 15))) * 8);
        sacc[mb] = __builtin_amdgcn_mfma_f32_32x32x16_bf16(kf, qf[ks], sacc[mb], 0, 0, 0);
      }
    }
    __builtin_amdgcn_s_setprio(0);

    // ---- softmax + in-register P pack (T12) ----
    const float* alsk = Alsf + kt * 64 + 4 * h;
    bf16x8 pfr[4];
#pragma unroll
    for (int mb = 0; mb < 2; ++mb) {
      float p[16];
#pragma unroll
      for (int g = 0; g < 4; ++g) {
        float4 av = *(const float4*)(alsk + mb * 32 + g * 8);
        p[g * 4 + 0] = __builtin_amdgcn_exp2f(sacc[mb][g * 4 + 0] * SCALE_L2 + av.x * LOG2E);
        p[g * 4 + 1] = __builtin_amdgcn_exp2f(sacc[mb][g * 4 + 1] * SCALE_L2 + av.y * LOG2E);
        p[g * 4 + 2] = __builtin_amdgcn_exp2f(sacc[mb][g * 4 + 2] * SCALE_L2 + av.z * LOG2E);
        p[g * 4 + 3] = __builtin_amdgcn_exp2f(sacc[mb][g * 4 + 3] * SCALE_L2 + av.w * LOG2E);
        l_acc += (p[g * 4 + 0] + p[g * 4 + 1]) + (p[g * 4 + 2] + p[g * 4 + 3]);
      }
      unsigned c0 = pkbf(p[0],  p[1]),  c1 = pkbf(p[2],  p[3]);
      unsigned c2 = pkbf(p[4],  p[5]),  c3 = pkbf(p[6],  p[7]);
      unsigned c4 = pkbf(p[8],  p[9]),  c5 = pkbf(p[10], p[11]);
      unsigned c6 = pkbf(p[12], p[13]), c7 = pkbf(p[14], p[15]);
      pl32swap(c0, c2);  pl32swap(c1, c3);
      pl32swap(c4, c6);  pl32swap(c5, c7);
      uint4 f0; f0.x = c0; f0.y = c1; f0.z = c2; f0.w = c3;
      uint4 f1; f1.x = c4; f1.y = c5; f1.z = c6; f1.w = c7;
      pfr[mb * 2 + 0] = __builtin_bit_cast(bf16x8, f0);
      pfr[mb * 2 + 1] = __builtin_bit_cast(bf16x8, f1);
    }

    // ---- O += P V ----
    __builtin_amdgcn_s_setprio(1);
#pragma unroll
    for (int ks2 = 0; ks2 < 4; ++ks2) {
      bf16x8 pf = pfr[ks2];
#pragma unroll
      for (int nb = 0; nb < 4; ++nb) {
        bf16x8 vf = *(const bf16x8*)(Vc + ((nb * 32 + l32) * 8 + ((ks2 * 2 + h) ^ (l32 & 7))) * 8);
        oacc[nb] = __builtin_amdgcn_mfma_f32_32x32x16_bf16(pf, vf, oacc[nb], 0, 0, 0);
      }
    }
    __builtin_amdgcn_s_setprio(0);

    // ---- boundary: reads retired, next tile landed, then issue tile t+2 ----
    asm volatile("s_waitcnt lgkmcnt(0) vmcnt(0)" ::: "memory");
    __builtin_amdgcn_s_barrier();
    if (kt + 2 < SEQ / 64) {
      unsigned short* kd = (kt & 1) ? Ks1 : Ks0;    // (kt+2)&1 parity
      unsigned short* vd = (kt & 1) ? Vts1 : Vts0;
      STAGE_KV(kt + 2, kd, vd);
    }
  }
#undef STAGE_KV

  float lf = l_acc + __shfl_xor(l_acc, 32, 64);
  float rinv[16];
#pragma unroll
  for (int reg = 0; reg < 16; ++reg) {
    int row = (reg & 3) + 8 * (reg >> 2) + 4 * h;
    rinv[reg] = 1.0f / __shfl(lf, row, 64);
  }

#pragma unroll
  for (int nb = 0; nb < 4; ++nb)
#pragma unroll
    for (int reg = 0; reg < 16; ++reg) {
      int row = (reg & 3) + 8 * (reg >> 2) + 4 * h;
      size_t qg = rowbase + q0 + w * 32 + row;
      Ctx[qg * HID + hh * HD + nb * 32 + l32] = f2bf(oacc[nb][reg] * rinv[reg]);
    }
}

// ---------------- launch ----------------
extern "C" void kernel_launch(void* const* d_in, const int* in_sizes, int n_in,
                              void* d_out, int out_size, void* d_ws, size_t ws_size,
                              hipStream_t stream) {
  const float* hidden   = (const float*)d_in[0];
  const float* residual = (const float*)d_in[1];
  const float* alibi    = (const float*)d_in[2];
  const float* Wq = (const float*)d_in[3];
  const float* bq = (const float*)d_in[4];
  const float* Wk = (const float*)d_in[5];
  const float* bk = (const float*)d_in[6];
  const float* Wv = (const float*)d_in[7];
  const float* bv = (const float*)d_in[8];
  const float* Wd = (const float*)d_in[9];
  const float* bd = (const float*)d_in[10];
  float* out = (float*)d_out;

  unsigned short* Xb    = (unsigned short*)d_ws;                    // 4096*2048
  unsigned short* Wqkvb = Xb + (size_t)MROWS * HID;                 // 6144*2048
  unsigned short* Wdb   = Wqkvb + (size_t)NQKV * HID;               // 2048*2048
  unsigned short* QKVb  = Wdb + (size_t)HID * HID;                  // 4096*6144
  unsigned short* Ctxb  = QKVb + (size_t)MROWS * NQKV;              // 4096*2048
  unsigned short* Vtb   = Wqkvb;  // Vt reuses Wqkvb region (dead after gemm_qkv)

  cvt_all_kernel<<<dim3(MROWS * HID / 4 / 256, 5), 256, 0, stream>>>(hidden, Wq, Wk, Wv, Wd, Xb);

  gemm_qkv384_kernel<<<256, 512, 0, stream>>>(Xb, Wqkvb, bq, bk, bv, QKVb);
  vtrans_kernel<<<dim3(SEQ / 64, HD / 64, BATCH * NHEAD), 256, 0, stream>>>(QKVb, Vtb);
  attn_kernel<<<512, 256, 0, stream>>>(QKVb, Vtb, alibi, Ctxb);
  gemm_out384_kernel<<<256, 512, 0, stream>>>(Ctxb, Wdb, bd, residual, out);
}

// Round 9
// 423.928 us; speedup vs baseline: 1.0475x; 1.0235x over previous
//
#include <hip/hip_runtime.h>

// ---------------- problem constants ----------------
#define HID   2048
#define NHEAD 16
#define HD    128
#define SEQ   2048
#define BATCH 2
#define MROWS (BATCH*SEQ)        // 4096
#define NQKV  (3*HID)            // 6144
#define INV_NORM 0.08838834764831845f
#define LOG2E    1.4426950408889634f
#define SCALE_L2 (INV_NORM*LOG2E)

typedef __attribute__((ext_vector_type(8)))  __bf16 bf16x8;
typedef __attribute__((ext_vector_type(4)))  float  f32x4;
typedef __attribute__((ext_vector_type(16))) float  f32x16;

typedef __attribute__((address_space(1))) void GV;
typedef __attribute__((address_space(3))) void LV;

__device__ __forceinline__ void async16(const void* g, void* l) {
  __builtin_amdgcn_global_load_lds((const GV*)g, (LV*)l, 16, 0, 0);
}

__device__ __forceinline__ unsigned short f2bf(float f) {
  unsigned u = __builtin_bit_cast(unsigned, f);
  u += 0x7FFFu + ((u >> 16) & 1u);       // RNE
  return (unsigned short)(u >> 16);
}

__device__ __forceinline__ unsigned pkbf(float a, float b) {
#if __has_builtin(__builtin_amdgcn_cvt_pk_bf16_f32)
  typedef __attribute__((ext_vector_type(2))) __bf16 bf16x2;
  bf16x2 r = __builtin_amdgcn_cvt_pk_bf16_f32(a, b);
  return __builtin_bit_cast(unsigned, r);
#else
  return (unsigned)f2bf(a) | ((unsigned)f2bf(b) << 16);
#endif
}

// exchange a's upper 32 lanes with b's lower 32 lanes (v_permlane32_swap_b32 a, b)
__device__ __forceinline__ void pl32swap(unsigned &a, unsigned &b) {
#if __has_builtin(__builtin_amdgcn_permlane32_swap)
  typedef __attribute__((ext_vector_type(2))) unsigned u32x2;
  u32x2 r = __builtin_amdgcn_permlane32_swap(a, b, false, false);
  a = r[0]; b = r[1];
#else
  asm volatile("v_permlane32_swap_b32 %0, %1" : "+v"(a), "+v"(b));
#endif
}

__device__ __forceinline__ void mfma16(f32x4& c, bf16x8 a, bf16x8 b) {
  c = __builtin_amdgcn_mfma_f32_16x16x32_bf16(a, b, c, 0, 0, 0);
}

// LDS fragment read with chunk-XOR swizzle (BK=64 -> 8 chunks of 16B per row)
__device__ __forceinline__ bf16x8 frag(const unsigned short* buf, int row, int chunk) {
  return *(const bf16x8*)(buf + ((row * 8 + (chunk ^ (row & 7))) << 3));
}

// ---------------- fp32 -> bf16 cast, flat exact grid (no empty blocks) ----------------
// Layout in Xb: [hidden 2^23][W0 2^22][W1][W2][W3]; total 25165824 elems = 24576 blocks.
__global__ __launch_bounds__(256) void cvt_all_kernel(
    const float* __restrict__ hidden,
    const float* __restrict__ W0, const float* __restrict__ W1,
    const float* __restrict__ W2, const float* __restrict__ W3,
    unsigned short* __restrict__ Xb) {
  size_t e = ((size_t)blockIdx.x * 256 + threadIdx.x) * 4;
  const float* src;
  if (e < (size_t)MROWS * HID) {
    src = hidden + e;
  } else {
    size_t r = e - (size_t)MROWS * HID;
    int sel = (int)(r >> 22);                 // HID*HID = 2^22
    size_t off = r & ((1u << 22) - 1);
    src = ((sel == 0) ? W0 : (sel == 1) ? W1 : (sel == 2) ? W2 : W3) + off;
  }
  float4 v = *(const float4*)src;
  ushort4 o;
  o.x = f2bf(v.x); o.y = f2bf(v.y); o.z = f2bf(v.z); o.w = f2bf(v.w);
  *(ushort4*)(Xb + e) = o;
}

// ---------------- GEMM 1: QKV projection, persistent 256-block, 3x(256x128) passes ----
// (R5 structure, unchanged: static buffer rotation, 1 barrier/phase, vmcnt(6) FIFO)
#define BUFU (24576)   // ushorts per buffer (48KB): A 16384 + B 8192
#define BUF3 (3 * BUFU)

__global__ __launch_bounds__(512, 2) void gemm_qkv384_kernel(
    const unsigned short* __restrict__ Xb, const unsigned short* __restrict__ Wb,
    const float* __restrict__ bq, const float* __restrict__ bk,
    const float* __restrict__ bv, unsigned short* __restrict__ Cout) {
  __shared__ __align__(16) unsigned short smem[BUF3];   // 144 KiB

  const int tid  = threadIdx.x;
  const int w    = tid >> 6;
  const int lane = tid & 63;
  const int l16  = lane & 15;
  const int quad = lane >> 4;
  const int wm   = (w & 3) * 64;    // 4 M-waves
  const int wn   = (w >> 2) * 64;   // 2 N-waves

  const int wg = blockIdx.x;
  const int sw = (wg & 7) * 32 + (wg >> 3);
  const int m0  = (sw & 15) * 256;
  const int rn0 = (sw >> 4) * 384;

  const int sr  = tid >> 3;
  const int scs = ((tid & 7) ^ (sr & 7)) * 8;
  const unsigned short* aBase = Xb + (size_t)(m0 + sr) * HID + scs;

#define STGA(UB, RB, KT)                                              \
  async16(aBase + (size_t)(RB) * HID + (KT),                          \
          (char*)smem + (UB) * 2 + (RB) * 128 + w * 1024)
#define STGB(UB, RB, KT)                                              \
  async16(bBase + (size_t)(RB) * HID + (KT),                          \
          (char*)smem + (UB) * 2 + 32768 + (RB) * 128 + w * 1024)

#define VM6  asm volatile("s_waitcnt vmcnt(6)" ::: "memory")
#define VM0  asm volatile("s_waitcnt vmcnt(0)" ::: "memory")

#define PHASE(UB, KK, STGBLK, WAITBLK)                                         \
  {                                                                            \
    const unsigned short* Ab = smem + (UB);                                    \
    const unsigned short* Bb = Ab + 16384;                                     \
    bf16x8 ta[4], tb[4];                                                       \
    ta[0] = frag(Ab, wm + l16, (KK) * 4 + quad);                               \
    _Pragma("unroll")                                                          \
    for (int j = 0; j < 4; ++j)  tb[j] = frag(Bb, wn + j * 16 + l16, (KK) * 4 + quad); \
    _Pragma("unroll")                                                          \
    for (int ii = 1; ii < 4; ++ii) ta[ii] = frag(Ab, wm + ii * 16 + l16, (KK) * 4 + quad); \
    STGBLK;                                                                    \
    __builtin_amdgcn_s_setprio(1);                                             \
    _Pragma("unroll")                                                          \
    for (int ii = 0; ii < 4; ++ii)                                             \
      _Pragma("unroll")                                                        \
      for (int j = 0; j < 4; ++j) mfma16(acc[ii][j], ta[ii], tb[j]);           \
    __builtin_amdgcn_s_setprio(0);                                             \
    asm volatile("s_waitcnt lgkmcnt(0)" ::: "memory");                         \
    WAITBLK;                                                                   \
    __builtin_amdgcn_s_barrier();                                              \
  }

  for (int p = 0; p < 3; ++p) {
    const unsigned short* bBase = Wb + (size_t)(rn0 + p * 128 + sr) * HID + scs;

    f32x4 acc[4][4];
    const f32x4 zero = {0.f, 0.f, 0.f, 0.f};
#pragma unroll
    for (int a = 0; a < 4; ++a)
#pragma unroll
      for (int j = 0; j < 4; ++j) acc[a][j] = zero;

    STGA(0, 0, 0);  STGA(0, 64, 0);  STGA(0, 128, 0);  STGA(0, 192, 0);
    STGB(0, 0, 0);  STGB(0, 64, 0);
    STGA(BUFU, 0, 64);  STGA(BUFU, 64, 64);  STGA(BUFU, 128, 64);  STGA(BUFU, 192, 64);
    STGB(BUFU, 0, 64);  STGB(BUFU, 64, 64);
    VM6;
    __builtin_amdgcn_s_barrier();

    int kb = 0;
    for (int g = 0; g < 5; ++g) {
      PHASE(0,        0, { STGA(2*BUFU, 0, kb+128); STGA(2*BUFU, 64, kb+128); STGA(2*BUFU, 128, kb+128); }, {});
      PHASE(0,        1, { STGA(2*BUFU, 192, kb+128); STGB(2*BUFU, 0, kb+128); STGB(2*BUFU, 64, kb+128); }, VM6);
      PHASE(BUFU,     0, { STGA(0, 0, kb+192); STGA(0, 64, kb+192); STGA(0, 128, kb+192); }, {});
      PHASE(BUFU,     1, { STGA(0, 192, kb+192); STGB(0, 0, kb+192); STGB(0, 64, kb+192); }, VM6);
      PHASE(2*BUFU,   0, { STGA(BUFU, 0, kb+256); STGA(BUFU, 64, kb+256); STGA(BUFU, 128, kb+256); }, {});
      PHASE(2*BUFU,   1, { STGA(BUFU, 192, kb+256); STGB(BUFU, 0, kb+256); STGB(BUFU, 64, kb+256); }, VM6);
      PHASE(0,        0, { STGA(2*BUFU, 0, kb+320); STGA(2*BUFU, 64, kb+320); STGA(2*BUFU, 128, kb+320); }, {});
      PHASE(0,        1, { STGA(2*BUFU, 192, kb+320); STGB(2*BUFU, 0, kb+320); STGB(2*BUFU, 64, kb+320); }, VM6);
      PHASE(BUFU,     0, { STGA(0, 0, kb+384); STGA(0, 64, kb+384); STGA(0, 128, kb+384); }, {});
      PHASE(BUFU,     1, { STGA(0, 192, kb+384); STGB(0, 0, kb+384); STGB(0, 64, kb+384); }, VM6);
      PHASE(2*BUFU,   0, { STGA(BUFU, 0, kb+448); STGA(BUFU, 64, kb+448); STGA(BUFU, 128, kb+448); }, {});
      PHASE(2*BUFU,   1, { STGA(BUFU, 192, kb+448); STGB(BUFU, 0, kb+448); STGB(BUFU, 64, kb+448); }, VM6);
      kb += 384;
    }

    PHASE(0,    0, {}, {});
    PHASE(0,    1, {}, VM0);
    PHASE(BUFU, 0, {}, {});
    PHASE(BUFU, 1, {}, {});

#pragma unroll
    for (int j = 0; j < 4; ++j) {
      int ng = rn0 + p * 128 + wn + j * 16 + l16;
      float bias = (ng < HID) ? bq[ng] : (ng < 2 * HID ? bk[ng - HID] : bv[ng - 2 * HID]);
#pragma unroll
      for (int a = 0; a < 4; ++a)
#pragma unroll
        for (int r = 0; r < 4; ++r) {
          int mg = m0 + wm + a * 16 + quad * 4 + r;
          Cout[(size_t)mg * NQKV + ng] = f2bf(acc[a][j][r] + bias);
        }
    }
  }
#undef STGA
#undef STGB
#undef PHASE
#undef VM6
#undef VM0
}

// ---------------- GEMM 2: out-proj, SAME persistent structure (single pass) ----------------
__global__ __launch_bounds__(512, 2) void gemm_out384_kernel(
    const unsigned short* __restrict__ Ctx, const unsigned short* __restrict__ Wdb,
    const float* __restrict__ bd, const float* __restrict__ Res,
    float* __restrict__ Out) {
  __shared__ __align__(16) unsigned short smem[BUF3];   // 144 KiB

  const int tid  = threadIdx.x;
  const int w    = tid >> 6;
  const int lane = tid & 63;
  const int l16  = lane & 15;
  const int quad = lane >> 4;
  const int wm   = (w & 3) * 64;
  const int wn   = (w >> 2) * 64;

  const int wg = blockIdx.x;
  const int sw = (wg & 7) * 32 + (wg >> 3);
  const int m0  = (sw & 15) * 256;
  const int rn0 = (sw >> 4) * 128;

  const int sr  = tid >> 3;
  const int scs = ((tid & 7) ^ (sr & 7)) * 8;
  const unsigned short* aBase = Ctx + (size_t)(m0 + sr) * HID + scs;
  const unsigned short* bBase = Wdb + (size_t)(rn0 + sr) * HID + scs;

#define STGA(UB, RB, KT)                                              \
  async16(aBase + (size_t)(RB) * HID + (KT),                          \
          (char*)smem + (UB) * 2 + (RB) * 128 + w * 1024)
#define STGB(UB, RB, KT)                                              \
  async16(bBase + (size_t)(RB) * HID + (KT),                          \
          (char*)smem + (UB) * 2 + 32768 + (RB) * 128 + w * 1024)

#define VM6  asm volatile("s_waitcnt vmcnt(6)" ::: "memory")
#define VM0  asm volatile("s_waitcnt vmcnt(0)" ::: "memory")

#define PHASE(UB, KK, STGBLK, WAITBLK)                                         \
  {                                                                            \
    const unsigned short* Ab = smem + (UB);                                    \
    const unsigned short* Bb = Ab + 16384;                                     \
    bf16x8 ta[4], tb[4];                                                       \
    ta[0] = frag(Ab, wm + l16, (KK) * 4 + quad);                               \
    _Pragma("unroll")                                                          \
    for (int j = 0; j < 4; ++j)  tb[j] = frag(Bb, wn + j * 16 + l16, (KK) * 4 + quad); \
    _Pragma("unroll")                                                          \
    for (int ii = 1; ii < 4; ++ii) ta[ii] = frag(Ab, wm + ii * 16 + l16, (KK) * 4 + quad); \
    STGBLK;                                                                    \
    __builtin_amdgcn_s_setprio(1);                                             \
    _Pragma("unroll")                                                          \
    for (int ii = 0; ii < 4; ++ii)                                             \
      _Pragma("unroll")                                                        \
      for (int j = 0; j < 4; ++j) mfma16(acc[ii][j], ta[ii], tb[j]);           \
    __builtin_amdgcn_s_setprio(0);                                             \
    asm volatile("s_waitcnt lgkmcnt(0)" ::: "memory");                         \
    WAITBLK;                                                                   \
    __builtin_amdgcn_s_barrier();                                              \
  }

  f32x4 acc[4][4];
  const f32x4 zero = {0.f, 0.f, 0.f, 0.f};
#pragma unroll
  for (int a = 0; a < 4; ++a)
#pragma unroll
    for (int j = 0; j < 4; ++j) acc[a][j] = zero;

  STGA(0, 0, 0);  STGA(0, 64, 0);  STGA(0, 128, 0);  STGA(0, 192, 0);
  STGB(0, 0, 0);  STGB(0, 64, 0);
  STGA(BUFU, 0, 64);  STGA(BUFU, 64, 64);  STGA(BUFU, 128, 64);  STGA(BUFU, 192, 64);
  STGB(BUFU, 0, 64);  STGB(BUFU, 64, 64);
  VM6;
  __builtin_amdgcn_s_barrier();

  int kb = 0;
  for (int g = 0; g < 5; ++g) {
    PHASE(0,        0, { STGA(2*BUFU, 0, kb+128); STGA(2*BUFU, 64, kb+128); STGA(2*BUFU, 128, kb+128); }, {});
    PHASE(0,        1, { STGA(2*BUFU, 192, kb+128); STGB(2*BUFU, 0, kb+128); STGB(2*BUFU, 64, kb+128); }, VM6);
    PHASE(BUFU,     0, { STGA(0, 0, kb+192); STGA(0, 64, kb+192); STGA(0, 128, kb+192); }, {});
    PHASE(BUFU,     1, { STGA(0, 192, kb+192); STGB(0, 0, kb+192); STGB(0, 64, kb+192); }, VM6);
    PHASE(2*BUFU,   0, { STGA(BUFU, 0, kb+256); STGA(BUFU, 64, kb+256); STGA(BUFU, 128, kb+256); }, {});
    PHASE(2*BUFU,   1, { STGA(BUFU, 192, kb+256); STGB(BUFU, 0, kb+256); STGB(BUFU, 64, kb+256); }, VM6);
    PHASE(0,        0, { STGA(2*BUFU, 0, kb+320); STGA(2*BUFU, 64, kb+320); STGA(2*BUFU, 128, kb+320); }, {});
    PHASE(0,        1, { STGA(2*BUFU, 192, kb+320); STGB(2*BUFU, 0, kb+320); STGB(2*BUFU, 64, kb+320); }, VM6);
    PHASE(BUFU,     0, { STGA(0, 0, kb+384); STGA(0, 64, kb+384); STGA(0, 128, kb+384); }, {});
    PHASE(BUFU,     1, { STGA(0, 192, kb+384); STGB(0, 0, kb+384); STGB(0, 64, kb+384); }, VM6);
    PHASE(2*BUFU,   0, { STGA(BUFU, 0, kb+448); STGA(BUFU, 64, kb+448); STGA(BUFU, 128, kb+448); }, {});
    PHASE(2*BUFU,   1, { STGA(BUFU, 192, kb+448); STGB(BUFU, 0, kb+448); STGB(BUFU, 64, kb+448); }, VM6);
    kb += 384;
  }

  PHASE(0,    0, {}, {});
  PHASE(0,    1, {}, VM0);
  PHASE(BUFU, 0, {}, {});
  PHASE(BUFU, 1, {}, {});

#pragma unroll
  for (int j = 0; j < 4; ++j) {
    int ng = rn0 + wn + j * 16 + l16;
    float bias = bd[ng];
#pragma unroll
    for (int a = 0; a < 4; ++a)
#pragma unroll
      for (int r = 0; r < 4; ++r) {
        int mg = m0 + wm + a * 16 + quad * 4 + r;
        size_t off = (size_t)mg * HID + ng;
        Out[off] = acc[a][j][r] + bias + Res[off];
      }
  }
#undef STGA
#undef STGB
#undef PHASE
#undef VM6
#undef VM0
}

// ---------------- V transpose: QKV V-part -> Vt[bh][d][s] ----------------
__global__ __launch_bounds__(256) void vtrans_kernel(const unsigned short* __restrict__ QKV,
                                                     unsigned short* __restrict__ Vt) {
  __shared__ __align__(16) unsigned short T[64][72];
  const int s0 = blockIdx.x * 64, d0 = blockIdx.y * 64, bh = blockIdx.z;
  const int b = bh >> 4, h = bh & 15;
  const int tid = threadIdx.x;
#pragma unroll
  for (int i = 0; i < 2; ++i) {
    int idx = i * 256 + tid;
    int r = idx >> 3, ch = idx & 7;
    const unsigned short* g = QKV + ((size_t)b * SEQ + s0 + r) * NQKV + 2 * HID + h * HD + d0 + ch * 8;
    *(uint4*)(&T[r][ch * 8]) = *(const uint4*)g;
  }
  __syncthreads();
#pragma unroll
  for (int i = 0; i < 2; ++i) {
    int idx = i * 256 + tid;
    int d = idx >> 3, ch = idx & 7;
    unsigned short v[8];
#pragma unroll
    for (int x = 0; x < 8; ++x) v[x] = T[ch * 8 + x][d];
    unsigned short* g = Vt + ((size_t)bh * HD + d0 + d) * SEQ + s0 + ch * 8;
    *(uint4*)g = *(const uint4*)v;
  }
}

// ---------------- flash attention: T15 double-pipeline (QK^T(t+1) || softmax(t)) ----------------
// XCD-pinned 1D grid 512. LDS: Ks0/Ks1 | Vts0/Vts1 | Als = 72KB -> 2 blocks/CU.
// Iter t: STAGE K(t+2) -> vmcnt(8) [drains V(t), K(t+1)] -> QK^T(t+1) into sacc_next
// (MFMA pipe) -> softmax(t) on sacc_prev (VALU, overlaps MFMA tail) -> PV(t)
// -> lgkm(0) -> barrier -> STAGE V(t+2).  1 barrier/iter; waited loads >=1 iter old.
// sA/sB ping-pong via 2x-unrolled loop (no register copies).
__global__ __launch_bounds__(256, 2) void attn_kernel(
    const unsigned short* __restrict__ QKV, const unsigned short* __restrict__ Vt,
    const float* __restrict__ alibi, unsigned short* __restrict__ Ctx) {
  __shared__ __align__(16) char smem[73728];
  unsigned short* Ks0  = (unsigned short*)smem;
  unsigned short* Ks1  = (unsigned short*)(smem + 16384);
  unsigned short* Vts0 = (unsigned short*)(smem + 32768);
  unsigned short* Vts1 = (unsigned short*)(smem + 49152);
  float*          Alsf = (float*)(smem + 65536);
  unsigned short* Qs   = (unsigned short*)smem;   // alias: Q staging (32 KB over Ks0+Ks1)

  const int tid = threadIdx.x, w = tid >> 6, lane = tid & 63;
  const int l32 = lane & 31, h = lane >> 5;
  // XCD-pinned decode: all 16 q-blocks of one bh share an XCD
  const int bid = blockIdx.x;
  const int t  = bid >> 3;
  const int q0 = (t & 15) * 128;
  const int bh = (bid & 7) + 8 * (t >> 4);
  const int b = bh >> 4, hh = bh & 15;
  const size_t rowbase = (size_t)b * SEQ;
  const float* ali = alibi + (size_t)bh * SEQ;
  const unsigned short* Vbh = Vt + (size_t)bh * HD * SEQ;

  // ---- stage Q (aliases Ks0+Ks1) + alibi row (8KB) ----
  {
    const unsigned short* qbase = QKV + (rowbase + q0) * NQKV + hh * HD;
#pragma unroll
    for (int i = 0; i < 8; ++i) {
      int slot = i * 256 + w * 64 + lane;
      int r = slot >> 4, c = (slot & 15) ^ (r & 15);
      async16(qbase + (size_t)r * NQKV + c * 8, (char*)Qs + (size_t)(i * 256 + w * 64) * 16);
    }
    const char* asrc = (const char*)ali;
#pragma unroll
    for (int i = 0; i < 2; ++i) {
      int slot = i * 256 + w * 64 + lane;
      async16(asrc + (size_t)slot * 16, (char*)Alsf + (size_t)(i * 256 + w * 64) * 16);
    }
  }
  __syncthreads();
  bf16x8 qf[8];
  {
    int qr = w * 32 + l32;
#pragma unroll
    for (int ks = 0; ks < 8; ++ks) {
      int c = (ks * 2 + h) ^ (qr & 15);
      qf[ks] = *(const bf16x8*)(Qs + (qr * 16 + c) * 8);
    }
  }

  f32x16 oacc[4];
  float l_acc = 0.f;
#pragma unroll
  for (int nb = 0; nb < 4; ++nb)
#pragma unroll
    for (int r = 0; r < 16; ++r) oacc[nb][r] = 0.f;

  __syncthreads();   // qf reads complete before K staging overwrites alias

#define STAGE_K(T, KD)                                                           \
  {                                                                              \
    const unsigned short* kbase = QKV + (rowbase + (size_t)(T) * 64) * NQKV + HID + hh * HD; \
    _Pragma("unroll")                                                            \
    for (int i = 0; i < 4; ++i) {                                                \
      int slot = i * 256 + w * 64 + lane;                                        \
      int r = slot >> 4, c = (slot & 15) ^ (r & 15);                             \
      async16(kbase + (size_t)r * NQKV + c * 8, (char*)(KD) + (size_t)(i * 256 + w * 64) * 16); \
    }                                                                            \
  }
#define STAGE_V(T, VD)                                                           \
  {                                                                              \
    const unsigned short* vbase = Vbh + (T) * 64;                                \
    _Pragma("unroll")                                                            \
    for (int i = 0; i < 4; ++i) {                                                \
      int slot = i * 256 + w * 64 + lane;                                        \
      int r = slot >> 3, c = (slot & 7) ^ (r & 7);                               \
      async16(vbase + (size_t)r * SEQ + c * 8, (char*)(VD) + (size_t)(i * 256 + w * 64) * 16); \
    }                                                                            \
  }

#define QKT(SACC, KBUF)                                                          \
  {                                                                              \
    _Pragma("unroll")                                                            \
    for (int mb = 0; mb < 2; ++mb)                                               \
      _Pragma("unroll")                                                          \
      for (int r = 0; r < 16; ++r) (SACC)[mb][r] = 0.f;                          \
    __builtin_amdgcn_s_setprio(1);                                               \
    _Pragma("unroll")                                                            \
    for (int ks = 0; ks < 8; ++ks)                                               \
      _Pragma("unroll")                                                          \
      for (int mb = 0; mb < 2; ++mb) {                                           \
        bf16x8 kf = *(const bf16x8*)((KBUF) + ((mb * 32 + l32) * 16 + ((ks * 2 + h) ^ (l32 & 15))) * 8); \
        (SACC)[mb] = __builtin_amdgcn_mfma_f32_32x32x16_bf16(kf, qf[ks], (SACC)[mb], 0, 0, 0); \
      }                                                                          \
    __builtin_amdgcn_s_setprio(0);                                               \
  }

#define SOFTMAX(SACC, KT, PFR)                                                   \
  {                                                                              \
    const float* alsk = Alsf + (KT) * 64 + 4 * h;                                \
    _Pragma("unroll")                                                            \
    for (int mb = 0; mb < 2; ++mb) {                                             \
      float p[16];                                                               \
      _Pragma("unroll")                                                          \
      for (int g = 0; g < 4; ++g) {                                              \
        float4 av = *(const float4*)(alsk + mb * 32 + g * 8);                    \
        p[g * 4 + 0] = __builtin_amdgcn_exp2f((SACC)[mb][g * 4 + 0] * SCALE_L2 + av.x * LOG2E); \
        p[g * 4 + 1] = __builtin_amdgcn_exp2f((SACC)[mb][g * 4 + 1] * SCALE_L2 + av.y * LOG2E); \
        p[g * 4 + 2] = __builtin_amdgcn_exp2f((SACC)[mb][g * 4 + 2] * SCALE_L2 + av.z * LOG2E); \
        p[g * 4 + 3] = __builtin_amdgcn_exp2f((SACC)[mb][g * 4 + 3] * SCALE_L2 + av.w * LOG2E); \
        l_acc += (p[g * 4 + 0] + p[g * 4 + 1]) + (p[g * 4 + 2] + p[g * 4 + 3]);  \
      }                                                                          \
      unsigned c0 = pkbf(p[0],  p[1]),  c1 = pkbf(p[2],  p[3]);                  \
      unsigned c2 = pkbf(p[4],  p[5]),  c3 = pkbf(p[6],  p[7]);                  \
      unsigned c4 = pkbf(p[8],  p[9]),  c5 = pkbf(p[10], p[11]);                 \
      unsigned c6 = pkbf(p[12], p[13]), c7 = pkbf(p[14], p[15]);                 \
      pl32swap(c0, c2);  pl32swap(c1, c3);                                       \
      pl32swap(c4, c6);  pl32swap(c5, c7);                                       \
      uint4 f0; f0.x = c0; f0.y = c1; f0.z = c2; f0.w = c3;                      \
      uint4 f1; f1.x = c4; f1.y = c5; f1.z = c6; f1.w = c7;                      \
      (PFR)[mb * 2 + 0] = __builtin_bit_cast(bf16x8, f0);                        \
      (PFR)[mb * 2 + 1] = __builtin_bit_cast(bf16x8, f1);                        \
    }                                                                            \
  }

#define PVOP(PFR, VBUF)                                                          \
  {                                                                              \
    __builtin_amdgcn_s_setprio(1);                                               \
    _Pragma("unroll")                                                            \
    for (int ks2 = 0; ks2 < 4; ++ks2) {                                          \
      bf16x8 pf = (PFR)[ks2];                                                    \
      _Pragma("unroll")                                                          \
      for (int nb = 0; nb < 4; ++nb) {                                           \
        bf16x8 vf = *(const bf16x8*)((VBUF) + ((nb * 32 + l32) * 8 + ((ks2 * 2 + h) ^ (l32 & 7))) * 8); \
        oacc[nb] = __builtin_amdgcn_mfma_f32_32x32x16_bf16(pf, vf, oacc[nb], 0, 0, 0); \
      }                                                                          \
    }                                                                            \
    __builtin_amdgcn_s_setprio(0);                                               \
  }

  // prologue: stage tiles 0,1; drain tile 0; compute QK^T(0); coherent point.
  STAGE_K(0, Ks0);  STAGE_V(0, Vts0);
  STAGE_K(1, Ks1);  STAGE_V(1, Vts1);
  asm volatile("s_waitcnt vmcnt(8)" ::: "memory");
  __builtin_amdgcn_s_barrier();

  f32x16 sA[2], sB[2];
  QKT(sA, Ks0);
  asm volatile("s_waitcnt lgkmcnt(0)" ::: "memory");
  __builtin_amdgcn_s_barrier();   // all waves' tile-0 K reads retired -> Ks0 stageable

  for (int kt = 0; kt < 30; kt += 2) {
    // even: cur tile kt (bufs 0), next tile kt+1 (bufs 1)
    STAGE_K(kt + 2, Ks0);
    asm volatile("s_waitcnt vmcnt(8)" ::: "memory");   // drains V(kt), K(kt+1)
    QKT(sB, Ks1);
    { bf16x8 pfr[4]; SOFTMAX(sA, kt, pfr); PVOP(pfr, Vts0); }
    asm volatile("s_waitcnt lgkmcnt(0)" ::: "memory");
    __builtin_amdgcn_s_barrier();
    STAGE_V(kt + 2, Vts0);
    // odd: cur tile kt+1 (bufs 1), next tile kt+2 (bufs 0)
    STAGE_K(kt + 3, Ks1);
    asm volatile("s_waitcnt vmcnt(8)" ::: "memory");   // drains V(kt+1), K(kt+2)
    QKT(sA, Ks0);
    { bf16x8 pfr[4]; SOFTMAX(sB, kt + 1, pfr); PVOP(pfr, Vts1); }
    asm volatile("s_waitcnt lgkmcnt(0)" ::: "memory");
    __builtin_amdgcn_s_barrier();
    STAGE_V(kt + 3, Vts1);
  }

  // kt = 30 (no tile-32 staging): outstanding [V30, K31, V31]
  asm volatile("s_waitcnt vmcnt(4)" ::: "memory");     // drains V(30), K(31)
  QKT(sB, Ks1);
  { bf16x8 pfr[4]; SOFTMAX(sA, 30, pfr); PVOP(pfr, Vts0); }
  asm volatile("s_waitcnt lgkmcnt(0) vmcnt(0)" ::: "memory");   // V(31) landed
  __builtin_amdgcn_s_barrier();
  // kt = 31
  { bf16x8 pfr[4]; SOFTMAX(sB, 31, pfr); PVOP(pfr, Vts1); }
  asm volatile("s_waitcnt lgkmcnt(0)" ::: "memory");

#undef STAGE_K
#undef STAGE_V
#undef QKT
#undef SOFTMAX
#undef PVOP

  float lf = l_acc + __shfl_xor(l_acc, 32, 64);
  float rinv[16];
#pragma unroll
  for (int reg = 0; reg < 16; ++reg) {
    int row = (reg & 3) + 8 * (reg >> 2) + 4 * h;
    rinv[reg] = 1.0f / __shfl(lf, row, 64);
  }

#pragma unroll
  for (int nb = 0; nb < 4; ++nb)
#pragma unroll
    for (int reg = 0; reg < 16; ++reg) {
      int row = (reg & 3) + 8 * (reg >> 2) + 4 * h;
      size_t qg = rowbase + q0 + w * 32 + row;
      Ctx[qg * HID + hh * HD + nb * 32 + l32] = f2bf(oacc[nb][reg] * rinv[reg]);
    }
}

// ---------------- launch ----------------
extern "C" void kernel_launch(void* const* d_in, const int* in_sizes, int n_in,
                              void* d_out, int out_size, void* d_ws, size_t ws_size,
                              hipStream_t stream) {
  const float* hidden   = (const float*)d_in[0];
  const float* residual = (const float*)d_in[1];
  const float* alibi    = (const float*)d_in[2];
  const float* Wq = (const float*)d_in[3];
  const float* bq = (const float*)d_in[4];
  const float* Wk = (const float*)d_in[5];
  const float* bk = (const float*)d_in[6];
  const float* Wv = (const float*)d_in[7];
  const float* bv = (const float*)d_in[8];
  const float* Wd = (const float*)d_in[9];
  const float* bd = (const float*)d_in[10];
  float* out = (float*)d_out;

  unsigned short* Xb    = (unsigned short*)d_ws;                    // 4096*2048
  unsigned short* Wqkvb = Xb + (size_t)MROWS * HID;                 // 6144*2048
  unsigned short* Wdb   = Wqkvb + (size_t)NQKV * HID;               // 2048*2048
  unsigned short* QKVb  = Wdb + (size_t)HID * HID;                  // 4096*6144
  unsigned short* Ctxb  = QKVb + (size_t)MROWS * NQKV;              // 4096*2048
  unsigned short* Vtb   = Wqkvb;  // Vt reuses Wqkvb region (dead after gemm_qkv)

  const int nTot = (MROWS * HID + 4 * HID * HID) / 4 / 256;   // 24576 blocks, exact
  cvt_all_kernel<<<nTot, 256, 0, stream>>>(hidden, Wq, Wk, Wv, Wd, Xb);

  gemm_qkv384_kernel<<<256, 512, 0, stream>>>(Xb, Wqkvb, bq, bk, bv, QKVb);
  vtrans_kernel<<<dim3(SEQ / 64, HD / 64, BATCH * NHEAD), 256, 0, stream>>>(QKVb, Vtb);
  attn_kernel<<<512, 256, 0, stream>>>(QKVb, Vtb, alibi, Ctxb);
  gemm_out384_kernel<<<256, 512, 0, stream>>>(Ctxb, Wdb, bd, residual, out);
}

// Round 10
// 409.467 us; speedup vs baseline: 1.0845x; 1.0353x over previous
//
#include <hip/hip_runtime.h>

// ---------------- problem constants ----------------
#define HID   2048
#define NHEAD 16
#define HD    128
#define SEQ   2048
#define BATCH 2
#define MROWS (BATCH*SEQ)        // 4096
#define NQKV  (3*HID)            // 6144
#define INV_NORM 0.08838834764831845f
#define LOG2E    1.4426950408889634f
#define SCALE_L2 (INV_NORM*LOG2E)

typedef __attribute__((ext_vector_type(8)))  __bf16 bf16x8;
typedef __attribute__((ext_vector_type(4)))  float  f32x4;
typedef __attribute__((ext_vector_type(16))) float  f32x16;

typedef __attribute__((address_space(1))) void GV;
typedef __attribute__((address_space(3))) void LV;

__device__ __forceinline__ void async16(const void* g, void* l) {
  __builtin_amdgcn_global_load_lds((const GV*)g, (LV*)l, 16, 0, 0);
}

__device__ __forceinline__ unsigned short f2bf(float f) {
  unsigned u = __builtin_bit_cast(unsigned, f);
  u += 0x7FFFu + ((u >> 16) & 1u);       // RNE
  return (unsigned short)(u >> 16);
}

__device__ __forceinline__ unsigned pkbf(float a, float b) {
#if __has_builtin(__builtin_amdgcn_cvt_pk_bf16_f32)
  typedef __attribute__((ext_vector_type(2))) __bf16 bf16x2;
  bf16x2 r = __builtin_amdgcn_cvt_pk_bf16_f32(a, b);
  return __builtin_bit_cast(unsigned, r);
#else
  return (unsigned)f2bf(a) | ((unsigned)f2bf(b) << 16);
#endif
}

// exchange a's upper 32 lanes with b's lower 32 lanes (v_permlane32_swap_b32 a, b)
__device__ __forceinline__ void pl32swap(unsigned &a, unsigned &b) {
#if __has_builtin(__builtin_amdgcn_permlane32_swap)
  typedef __attribute__((ext_vector_type(2))) unsigned u32x2;
  u32x2 r = __builtin_amdgcn_permlane32_swap(a, b, false, false);
  a = r[0]; b = r[1];
#else
  asm volatile("v_permlane32_swap_b32 %0, %1" : "+v"(a), "+v"(b));
#endif
}

__device__ __forceinline__ void mfma16(f32x4& c, bf16x8 a, bf16x8 b) {
  c = __builtin_amdgcn_mfma_f32_16x16x32_bf16(a, b, c, 0, 0, 0);
}

// LDS fragment read with chunk-XOR swizzle (BK=64 -> 8 chunks of 16B per row)
__device__ __forceinline__ bf16x8 frag(const unsigned short* buf, int row, int chunk) {
  return *(const bf16x8*)(buf + ((row * 8 + (chunk ^ (row & 7))) << 3));
}

// ---------------- fp32 -> bf16 cast, flat exact grid (no empty blocks) ----------------
__global__ __launch_bounds__(256) void cvt_all_kernel(
    const float* __restrict__ hidden,
    const float* __restrict__ W0, const float* __restrict__ W1,
    const float* __restrict__ W2, const float* __restrict__ W3,
    unsigned short* __restrict__ Xb) {
  size_t e = ((size_t)blockIdx.x * 256 + threadIdx.x) * 4;
  const float* src;
  if (e < (size_t)MROWS * HID) {
    src = hidden + e;
  } else {
    size_t r = e - (size_t)MROWS * HID;
    int sel = (int)(r >> 22);                 // HID*HID = 2^22
    size_t off = r & ((1u << 22) - 1);
    src = ((sel == 0) ? W0 : (sel == 1) ? W1 : (sel == 2) ? W2 : W3) + off;
  }
  float4 v = *(const float4*)src;
  ushort4 o;
  o.x = f2bf(v.x); o.y = f2bf(v.y); o.z = f2bf(v.z); o.w = f2bf(v.w);
  *(ushort4*)(Xb + e) = o;
}

// ---------------- GEMM 1: QKV projection, persistent 256-block, 3x(256x128) passes ----
// R10: fused V-transpose epilogue. If Vt != nullptr, V-columns (ng>=2*HID) are written
// DIRECTLY in Vt[bh][d][s] layout (packed 8B stores; r=0..3 are s-consecutive) and the
// QKVb V-section is skipped. b = mg>>11 is block-constant (256-row bands don't straddle
// the 2048 boundary). Branch is wave-uniform (ng group 16-aligned, 4096 % 16 == 0).
#define BUFU (24576)   // ushorts per buffer (48KB): A 16384 + B 8192
#define BUF3 (3 * BUFU)

__global__ __launch_bounds__(512, 2) void gemm_qkv384_kernel(
    const unsigned short* __restrict__ Xb, const unsigned short* __restrict__ Wb,
    const float* __restrict__ bq, const float* __restrict__ bk,
    const float* __restrict__ bv, unsigned short* __restrict__ Cout,
    unsigned short* __restrict__ Vt) {
  __shared__ __align__(16) unsigned short smem[BUF3];   // 144 KiB

  const int tid  = threadIdx.x;
  const int w    = tid >> 6;
  const int lane = tid & 63;
  const int l16  = lane & 15;
  const int quad = lane >> 4;
  const int wm   = (w & 3) * 64;    // 4 M-waves
  const int wn   = (w >> 2) * 64;   // 2 N-waves

  const int wg = blockIdx.x;
  const int sw = (wg & 7) * 32 + (wg >> 3);
  const int m0  = (sw & 15) * 256;
  const int rn0 = (sw >> 4) * 384;

  const int sr  = tid >> 3;
  const int scs = ((tid & 7) ^ (sr & 7)) * 8;
  const unsigned short* aBase = Xb + (size_t)(m0 + sr) * HID + scs;

#define STGA(UB, RB, KT)                                              \
  async16(aBase + (size_t)(RB) * HID + (KT),                          \
          (char*)smem + (UB) * 2 + (RB) * 128 + w * 1024)
#define STGB(UB, RB, KT)                                              \
  async16(bBase + (size_t)(RB) * HID + (KT),                          \
          (char*)smem + (UB) * 2 + 32768 + (RB) * 128 + w * 1024)

#define VM6  asm volatile("s_waitcnt vmcnt(6)" ::: "memory")
#define VM0  asm volatile("s_waitcnt vmcnt(0)" ::: "memory")

#define PHASE(UB, KK, STGBLK, WAITBLK)                                         \
  {                                                                            \
    const unsigned short* Ab = smem + (UB);                                    \
    const unsigned short* Bb = Ab + 16384;                                     \
    bf16x8 ta[4], tb[4];                                                       \
    ta[0] = frag(Ab, wm + l16, (KK) * 4 + quad);                               \
    _Pragma("unroll")                                                          \
    for (int j = 0; j < 4; ++j)  tb[j] = frag(Bb, wn + j * 16 + l16, (KK) * 4 + quad); \
    _Pragma("unroll")                                                          \
    for (int ii = 1; ii < 4; ++ii) ta[ii] = frag(Ab, wm + ii * 16 + l16, (KK) * 4 + quad); \
    STGBLK;                                                                    \
    __builtin_amdgcn_s_setprio(1);                                             \
    _Pragma("unroll")                                                          \
    for (int ii = 0; ii < 4; ++ii)                                             \
      _Pragma("unroll")                                                        \
      for (int j = 0; j < 4; ++j) mfma16(acc[ii][j], ta[ii], tb[j]);           \
    __builtin_amdgcn_s_setprio(0);                                             \
    asm volatile("s_waitcnt lgkmcnt(0)" ::: "memory");                         \
    WAITBLK;                                                                   \
    __builtin_amdgcn_s_barrier();                                              \
  }

  for (int p = 0; p < 3; ++p) {
    const unsigned short* bBase = Wb + (size_t)(rn0 + p * 128 + sr) * HID + scs;

    f32x4 acc[4][4];
    const f32x4 zero = {0.f, 0.f, 0.f, 0.f};
#pragma unroll
    for (int a = 0; a < 4; ++a)
#pragma unroll
      for (int j = 0; j < 4; ++j) acc[a][j] = zero;

    STGA(0, 0, 0);  STGA(0, 64, 0);  STGA(0, 128, 0);  STGA(0, 192, 0);
    STGB(0, 0, 0);  STGB(0, 64, 0);
    STGA(BUFU, 0, 64);  STGA(BUFU, 64, 64);  STGA(BUFU, 128, 64);  STGA(BUFU, 192, 64);
    STGB(BUFU, 0, 64);  STGB(BUFU, 64, 64);
    VM6;
    __builtin_amdgcn_s_barrier();

    int kb = 0;
    for (int g = 0; g < 5; ++g) {
      PHASE(0,        0, { STGA(2*BUFU, 0, kb+128); STGA(2*BUFU, 64, kb+128); STGA(2*BUFU, 128, kb+128); }, {});
      PHASE(0,        1, { STGA(2*BUFU, 192, kb+128); STGB(2*BUFU, 0, kb+128); STGB(2*BUFU, 64, kb+128); }, VM6);
      PHASE(BUFU,     0, { STGA(0, 0, kb+192); STGA(0, 64, kb+192); STGA(0, 128, kb+192); }, {});
      PHASE(BUFU,     1, { STGA(0, 192, kb+192); STGB(0, 0, kb+192); STGB(0, 64, kb+192); }, VM6);
      PHASE(2*BUFU,   0, { STGA(BUFU, 0, kb+256); STGA(BUFU, 64, kb+256); STGA(BUFU, 128, kb+256); }, {});
      PHASE(2*BUFU,   1, { STGA(BUFU, 192, kb+256); STGB(BUFU, 0, kb+256); STGB(BUFU, 64, kb+256); }, VM6);
      PHASE(0,        0, { STGA(2*BUFU, 0, kb+320); STGA(2*BUFU, 64, kb+320); STGA(2*BUFU, 128, kb+320); }, {});
      PHASE(0,        1, { STGA(2*BUFU, 192, kb+320); STGB(2*BUFU, 0, kb+320); STGB(2*BUFU, 64, kb+320); }, VM6);
      PHASE(BUFU,     0, { STGA(0, 0, kb+384); STGA(0, 64, kb+384); STGA(0, 128, kb+384); }, {});
      PHASE(BUFU,     1, { STGA(0, 192, kb+384); STGB(0, 0, kb+384); STGB(0, 64, kb+384); }, VM6);
      PHASE(2*BUFU,   0, { STGA(BUFU, 0, kb+448); STGA(BUFU, 64, kb+448); STGA(BUFU, 128, kb+448); }, {});
      PHASE(2*BUFU,   1, { STGA(BUFU, 192, kb+448); STGB(BUFU, 0, kb+448); STGB(BUFU, 64, kb+448); }, VM6);
      kb += 384;
    }

    PHASE(0,    0, {}, {});
    PHASE(0,    1, {}, VM0);
    PHASE(BUFU, 0, {}, {});
    PHASE(BUFU, 1, {}, {});

#pragma unroll
    for (int j = 0; j < 4; ++j) {
      int ng = rn0 + p * 128 + wn + j * 16 + l16;
      float bias = (ng < HID) ? bq[ng] : (ng < 2 * HID ? bk[ng - HID] : bv[ng - 2 * HID]);
      if (Vt != nullptr && ng >= 2 * HID) {
        // fused V-transpose: Vt[(b*16+h)*128 + d][s], s-consecutive r packed 8B
        const int vidx = ng - 2 * HID;
        const int bb = m0 >> 11;
        unsigned short* vrow = Vt
            + ((size_t)((bb * 16 + (vidx >> 7)) * 128 + (vidx & 127))) * SEQ
            + (m0 & 2047) + wm + quad * 4;
#pragma unroll
        for (int a = 0; a < 4; ++a) {
          ushort4 pk4;
          pk4.x = f2bf(acc[a][j][0] + bias);
          pk4.y = f2bf(acc[a][j][1] + bias);
          pk4.z = f2bf(acc[a][j][2] + bias);
          pk4.w = f2bf(acc[a][j][3] + bias);
          *(ushort4*)(vrow + a * 16) = pk4;
        }
      } else {
#pragma unroll
        for (int a = 0; a < 4; ++a)
#pragma unroll
          for (int r = 0; r < 4; ++r) {
            int mg = m0 + wm + a * 16 + quad * 4 + r;
            Cout[(size_t)mg * NQKV + ng] = f2bf(acc[a][j][r] + bias);
          }
      }
    }
  }
#undef STGA
#undef STGB
#undef PHASE
#undef VM6
#undef VM0
}

// ---------------- GEMM 2: out-proj, SAME persistent structure (single pass) ----------------
__global__ __launch_bounds__(512, 2) void gemm_out384_kernel(
    const unsigned short* __restrict__ Ctx, const unsigned short* __restrict__ Wdb,
    const float* __restrict__ bd, const float* __restrict__ Res,
    float* __restrict__ Out) {
  __shared__ __align__(16) unsigned short smem[BUF3];   // 144 KiB

  const int tid  = threadIdx.x;
  const int w    = tid >> 6;
  const int lane = tid & 63;
  const int l16  = lane & 15;
  const int quad = lane >> 4;
  const int wm   = (w & 3) * 64;
  const int wn   = (w >> 2) * 64;

  const int wg = blockIdx.x;
  const int sw = (wg & 7) * 32 + (wg >> 3);
  const int m0  = (sw & 15) * 256;
  const int rn0 = (sw >> 4) * 128;

  const int sr  = tid >> 3;
  const int scs = ((tid & 7) ^ (sr & 7)) * 8;
  const unsigned short* aBase = Ctx + (size_t)(m0 + sr) * HID + scs;
  const unsigned short* bBase = Wdb + (size_t)(rn0 + sr) * HID + scs;

#define STGA(UB, RB, KT)                                              \
  async16(aBase + (size_t)(RB) * HID + (KT),                          \
          (char*)smem + (UB) * 2 + (RB) * 128 + w * 1024)
#define STGB(UB, RB, KT)                                              \
  async16(bBase + (size_t)(RB) * HID + (KT),                          \
          (char*)smem + (UB) * 2 + 32768 + (RB) * 128 + w * 1024)

#define VM6  asm volatile("s_waitcnt vmcnt(6)" ::: "memory")
#define VM0  asm volatile("s_waitcnt vmcnt(0)" ::: "memory")

#define PHASE(UB, KK, STGBLK, WAITBLK)                                         \
  {                                                                            \
    const unsigned short* Ab = smem + (UB);                                    \
    const unsigned short* Bb = Ab + 16384;                                     \
    bf16x8 ta[4], tb[4];                                                       \
    ta[0] = frag(Ab, wm + l16, (KK) * 4 + quad);                               \
    _Pragma("unroll")                                                          \
    for (int j = 0; j < 4; ++j)  tb[j] = frag(Bb, wn + j * 16 + l16, (KK) * 4 + quad); \
    _Pragma("unroll")                                                          \
    for (int ii = 1; ii < 4; ++ii) ta[ii] = frag(Ab, wm + ii * 16 + l16, (KK) * 4 + quad); \
    STGBLK;                                                                    \
    __builtin_amdgcn_s_setprio(1);                                             \
    _Pragma("unroll")                                                          \
    for (int ii = 0; ii < 4; ++ii)                                             \
      _Pragma("unroll")                                                        \
      for (int j = 0; j < 4; ++j) mfma16(acc[ii][j], ta[ii], tb[j]);           \
    __builtin_amdgcn_s_setprio(0);                                             \
    asm volatile("s_waitcnt lgkmcnt(0)" ::: "memory");                         \
    WAITBLK;                                                                   \
    __builtin_amdgcn_s_barrier();                                              \
  }

  f32x4 acc[4][4];
  const f32x4 zero = {0.f, 0.f, 0.f, 0.f};
#pragma unroll
  for (int a = 0; a < 4; ++a)
#pragma unroll
    for (int j = 0; j < 4; ++j) acc[a][j] = zero;

  STGA(0, 0, 0);  STGA(0, 64, 0);  STGA(0, 128, 0);  STGA(0, 192, 0);
  STGB(0, 0, 0);  STGB(0, 64, 0);
  STGA(BUFU, 0, 64);  STGA(BUFU, 64, 64);  STGA(BUFU, 128, 64);  STGA(BUFU, 192, 64);
  STGB(BUFU, 0, 64);  STGB(BUFU, 64, 64);
  VM6;
  __builtin_amdgcn_s_barrier();

  int kb = 0;
  for (int g = 0; g < 5; ++g) {
    PHASE(0,        0, { STGA(2*BUFU, 0, kb+128); STGA(2*BUFU, 64, kb+128); STGA(2*BUFU, 128, kb+128); }, {});
    PHASE(0,        1, { STGA(2*BUFU, 192, kb+128); STGB(2*BUFU, 0, kb+128); STGB(2*BUFU, 64, kb+128); }, VM6);
    PHASE(BUFU,     0, { STGA(0, 0, kb+192); STGA(0, 64, kb+192); STGA(0, 128, kb+192); }, {});
    PHASE(BUFU,     1, { STGA(0, 192, kb+192); STGB(0, 0, kb+192); STGB(0, 64, kb+192); }, VM6);
    PHASE(2*BUFU,   0, { STGA(BUFU, 0, kb+256); STGA(BUFU, 64, kb+256); STGA(BUFU, 128, kb+256); }, {});
    PHASE(2*BUFU,   1, { STGA(BUFU, 192, kb+256); STGB(BUFU, 0, kb+256); STGB(BUFU, 64, kb+256); }, VM6);
    PHASE(0,        0, { STGA(2*BUFU, 0, kb+320); STGA(2*BUFU, 64, kb+320); STGA(2*BUFU, 128, kb+320); }, {});
    PHASE(0,        1, { STGA(2*BUFU, 192, kb+320); STGB(2*BUFU, 0, kb+320); STGB(2*BUFU, 64, kb+320); }, VM6);
    PHASE(BUFU,     0, { STGA(0, 0, kb+384); STGA(0, 64, kb+384); STGA(0, 128, kb+384); }, {});
    PHASE(BUFU,     1, { STGA(0, 192, kb+384); STGB(0, 0, kb+384); STGB(0, 64, kb+384); }, VM6);
    PHASE(2*BUFU,   0, { STGA(BUFU, 0, kb+448); STGA(BUFU, 64, kb+448); STGA(BUFU, 128, kb+448); }, {});
    PHASE(2*BUFU,   1, { STGA(BUFU, 192, kb+448); STGB(BUFU, 0, kb+448); STGB(BUFU, 64, kb+448); }, VM6);
    kb += 384;
  }

  PHASE(0,    0, {}, {});
  PHASE(0,    1, {}, VM0);
  PHASE(BUFU, 0, {}, {});
  PHASE(BUFU, 1, {}, {});

#pragma unroll
  for (int j = 0; j < 4; ++j) {
    int ng = rn0 + wn + j * 16 + l16;
    float bias = bd[ng];
#pragma unroll
    for (int a = 0; a < 4; ++a)
#pragma unroll
      for (int r = 0; r < 4; ++r) {
        int mg = m0 + wm + a * 16 + quad * 4 + r;
        size_t off = (size_t)mg * HID + ng;
        Out[off] = acc[a][j][r] + bias + Res[off];
      }
  }
#undef STGA
#undef STGB
#undef PHASE
#undef VM6
#undef VM0
}

// ---------------- V transpose (FALLBACK only, when ws too small for fused Vt) ----------------
__global__ __launch_bounds__(256) void vtrans_kernel(const unsigned short* __restrict__ QKV,
                                                     unsigned short* __restrict__ Vt) {
  __shared__ __align__(16) unsigned short T[64][72];
  const int s0 = blockIdx.x * 64, d0 = blockIdx.y * 64, bh = blockIdx.z;
  const int b = bh >> 4, h = bh & 15;
  const int tid = threadIdx.x;
#pragma unroll
  for (int i = 0; i < 2; ++i) {
    int idx = i * 256 + tid;
    int r = idx >> 3, ch = idx & 7;
    const unsigned short* g = QKV + ((size_t)b * SEQ + s0 + r) * NQKV + 2 * HID + h * HD + d0 + ch * 8;
    *(uint4*)(&T[r][ch * 8]) = *(const uint4*)g;
  }
  __syncthreads();
#pragma unroll
  for (int i = 0; i < 2; ++i) {
    int idx = i * 256 + tid;
    int d = idx >> 3, ch = idx & 7;
    unsigned short v[8];
#pragma unroll
    for (int x = 0; x < 8; ++x) v[x] = T[ch * 8 + x][d];
    unsigned short* g = Vt + ((size_t)bh * HD + d0 + d) * SEQ + s0 + ch * 8;
    *(uint4*)g = *(const uint4*)v;
  }
}

// ---------------- flash attention: T15 double-pipeline (unchanged from R9) ----------------
__global__ __launch_bounds__(256, 2) void attn_kernel(
    const unsigned short* __restrict__ QKV, const unsigned short* __restrict__ Vt,
    const float* __restrict__ alibi, unsigned short* __restrict__ Ctx) {
  __shared__ __align__(16) char smem[73728];
  unsigned short* Ks0  = (unsigned short*)smem;
  unsigned short* Ks1  = (unsigned short*)(smem + 16384);
  unsigned short* Vts0 = (unsigned short*)(smem + 32768);
  unsigned short* Vts1 = (unsigned short*)(smem + 49152);
  float*          Alsf = (float*)(smem + 65536);
  unsigned short* Qs   = (unsigned short*)smem;   // alias: Q staging (32 KB over Ks0+Ks1)

  const int tid = threadIdx.x, w = tid >> 6, lane = tid & 63;
  const int l32 = lane & 31, h = lane >> 5;
  const int bid = blockIdx.x;
  const int t  = bid >> 3;
  const int q0 = (t & 15) * 128;
  const int bh = (bid & 7) + 8 * (t >> 4);
  const int b = bh >> 4, hh = bh & 15;
  const size_t rowbase = (size_t)b * SEQ;
  const float* ali = alibi + (size_t)bh * SEQ;
  const unsigned short* Vbh = Vt + (size_t)bh * HD * SEQ;

  {
    const unsigned short* qbase = QKV + (rowbase + q0) * NQKV + hh * HD;
#pragma unroll
    for (int i = 0; i < 8; ++i) {
      int slot = i * 256 + w * 64 + lane;
      int r = slot >> 4, c = (slot & 15) ^ (r & 15);
      async16(qbase + (size_t)r * NQKV + c * 8, (char*)Qs + (size_t)(i * 256 + w * 64) * 16);
    }
    const char* asrc = (const char*)ali;
#pragma unroll
    for (int i = 0; i < 2; ++i) {
      int slot = i * 256 + w * 64 + lane;
      async16(asrc + (size_t)slot * 16, (char*)Alsf + (size_t)(i * 256 + w * 64) * 16);
    }
  }
  __syncthreads();
  bf16x8 qf[8];
  {
    int qr = w * 32 + l32;
#pragma unroll
    for (int ks = 0; ks < 8; ++ks) {
      int c = (ks * 2 + h) ^ (qr & 15);
      qf[ks] = *(const bf16x8*)(Qs + (qr * 16 + c) * 8);
    }
  }

  f32x16 oacc[4];
  float l_acc = 0.f;
#pragma unroll
  for (int nb = 0; nb < 4; ++nb)
#pragma unroll
    for (int r = 0; r < 16; ++r) oacc[nb][r] = 0.f;

  __syncthreads();

#define STAGE_K(T, KD)                                                           \
  {                                                                              \
    const unsigned short* kbase = QKV + (rowbase + (size_t)(T) * 64) * NQKV + HID + hh * HD; \
    _Pragma("unroll")                                                            \
    for (int i = 0; i < 4; ++i) {                                                \
      int slot = i * 256 + w * 64 + lane;                                        \
      int r = slot >> 4, c = (slot & 15) ^ (r & 15);                             \
      async16(kbase + (size_t)r * NQKV + c * 8, (char*)(KD) + (size_t)(i * 256 + w * 64) * 16); \
    }                                                                            \
  }
#define STAGE_V(T, VD)                                                           \
  {                                                                              \
    const unsigned short* vbase = Vbh + (T) * 64;                                \
    _Pragma("unroll")                                                            \
    for (int i = 0; i < 4; ++i) {                                                \
      int slot = i * 256 + w * 64 + lane;                                        \
      int r = slot >> 3, c = (slot & 7) ^ (r & 7);                               \
      async16(vbase + (size_t)r * SEQ + c * 8, (char*)(VD) + (size_t)(i * 256 + w * 64) * 16); \
    }                                                                            \
  }

#define QKT(SACC, KBUF)                                                          \
  {                                                                              \
    _Pragma("unroll")                                                            \
    for (int mb = 0; mb < 2; ++mb)                                               \
      _Pragma("unroll")                                                          \
      for (int r = 0; r < 16; ++r) (SACC)[mb][r] = 0.f;                          \
    __builtin_amdgcn_s_setprio(1);                                               \
    _Pragma("unroll")                                                            \
    for (int ks = 0; ks < 8; ++ks)                                               \
      _Pragma("unroll")                                                          \
      for (int mb = 0; mb < 2; ++mb) {                                           \
        bf16x8 kf = *(const bf16x8*)((KBUF) + ((mb * 32 + l32) * 16 + ((ks * 2 + h) ^ (l32 & 15))) * 8); \
        (SACC)[mb] = __builtin_amdgcn_mfma_f32_32x32x16_bf16(kf, qf[ks], (SACC)[mb], 0, 0, 0); \
      }                                                                          \
    __builtin_amdgcn_s_setprio(0);                                               \
  }

#define SOFTMAX(SACC, KT, PFR)                                                   \
  {                                                                              \
    const float* alsk = Alsf + (KT) * 64 + 4 * h;                                \
    _Pragma("unroll")                                                            \
    for (int mb = 0; mb < 2; ++mb) {                                             \
      float p[16];                                                               \
      _Pragma("unroll")                                                          \
      for (int g = 0; g < 4; ++g) {                                              \
        float4 av = *(const float4*)(alsk + mb * 32 + g * 8);                    \
        p[g * 4 + 0] = __builtin_amdgcn_exp2f((SACC)[mb][g * 4 + 0] * SCALE_L2 + av.x * LOG2E); \
        p[g * 4 + 1] = __builtin_amdgcn_exp2f((SACC)[mb][g * 4 + 1] * SCALE_L2 + av.y * LOG2E); \
        p[g * 4 + 2] = __builtin_amdgcn_exp2f((SACC)[mb][g * 4 + 2] * SCALE_L2 + av.z * LOG2E); \
        p[g * 4 + 3] = __builtin_amdgcn_exp2f((SACC)[mb][g * 4 + 3] * SCALE_L2 + av.w * LOG2E); \
        l_acc += (p[g * 4 + 0] + p[g * 4 + 1]) + (p[g * 4 + 2] + p[g * 4 + 3]);  \
      }                                                                          \
      unsigned c0 = pkbf(p[0],  p[1]),  c1 = pkbf(p[2],  p[3]);                  \
      unsigned c2 = pkbf(p[4],  p[5]),  c3 = pkbf(p[6],  p[7]);                  \
      unsigned c4 = pkbf(p[8],  p[9]),  c5 = pkbf(p[10], p[11]);                 \
      unsigned c6 = pkbf(p[12], p[13]), c7 = pkbf(p[14], p[15]);                 \
      pl32swap(c0, c2);  pl32swap(c1, c3);                                       \
      pl32swap(c4, c6);  pl32swap(c5, c7);                                       \
      uint4 f0; f0.x = c0; f0.y = c1; f0.z = c2; f0.w = c3;                      \
      uint4 f1; f1.x = c4; f1.y = c5; f1.z = c6; f1.w = c7;                      \
      (PFR)[mb * 2 + 0] = __builtin_bit_cast(bf16x8, f0);                        \
      (PFR)[mb * 2 + 1] = __builtin_bit_cast(bf16x8, f1);                        \
    }                                                                            \
  }

#define PVOP(PFR, VBUF)                                                          \
  {                                                                              \
    __builtin_amdgcn_s_setprio(1);                                               \
    _Pragma("unroll")                                                            \
    for (int ks2 = 0; ks2 < 4; ++ks2) {                                          \
      bf16x8 pf = (PFR)[ks2];                                                    \
      _Pragma("unroll")                                                          \
      for (int nb = 0; nb < 4; ++nb) {                                           \
        bf16x8 vf = *(const bf16x8*)((VBUF) + ((nb * 32 + l32) * 8 + ((ks2 * 2 + h) ^ (l32 & 7))) * 8); \
        oacc[nb] = __builtin_amdgcn_mfma_f32_32x32x16_bf16(pf, vf, oacc[nb], 0, 0, 0); \
      }                                                                          \
    }                                                                            \
    __builtin_amdgcn_s_setprio(0);                                               \
  }

  STAGE_K(0, Ks0);  STAGE_V(0, Vts0);
  STAGE_K(1, Ks1);  STAGE_V(1, Vts1);
  asm volatile("s_waitcnt vmcnt(8)" ::: "memory");
  __builtin_amdgcn_s_barrier();

  f32x16 sA[2], sB[2];
  QKT(sA, Ks0);
  asm volatile("s_waitcnt lgkmcnt(0)" ::: "memory");
  __builtin_amdgcn_s_barrier();

  for (int kt = 0; kt < 30; kt += 2) {
    STAGE_K(kt + 2, Ks0);
    asm volatile("s_waitcnt vmcnt(8)" ::: "memory");
    QKT(sB, Ks1);
    { bf16x8 pfr[4]; SOFTMAX(sA, kt, pfr); PVOP(pfr, Vts0); }
    asm volatile("s_waitcnt lgkmcnt(0)" ::: "memory");
    __builtin_amdgcn_s_barrier();
    STAGE_V(kt + 2, Vts0);
    STAGE_K(kt + 3, Ks1);
    asm volatile("s_waitcnt vmcnt(8)" ::: "memory");
    QKT(sA, Ks0);
    { bf16x8 pfr[4]; SOFTMAX(sB, kt + 1, pfr); PVOP(pfr, Vts1); }
    asm volatile("s_waitcnt lgkmcnt(0)" ::: "memory");
    __builtin_amdgcn_s_barrier();
    STAGE_V(kt + 3, Vts1);
  }

  asm volatile("s_waitcnt vmcnt(4)" ::: "memory");
  QKT(sB, Ks1);
  { bf16x8 pfr[4]; SOFTMAX(sA, 30, pfr); PVOP(pfr, Vts0); }
  asm volatile("s_waitcnt lgkmcnt(0) vmcnt(0)" ::: "memory");
  __builtin_amdgcn_s_barrier();
  { bf16x8 pfr[4]; SOFTMAX(sB, 31, pfr); PVOP(pfr, Vts1); }
  asm volatile("s_waitcnt lgkmcnt(0)" ::: "memory");

#undef STAGE_K
#undef STAGE_V
#undef QKT
#undef SOFTMAX
#undef PVOP

  float lf = l_acc + __shfl_xor(l_acc, 32, 64);
  float rinv[16];
#pragma unroll
  for (int reg = 0; reg < 16; ++reg) {
    int row = (reg & 3) + 8 * (reg >> 2) + 4 * h;
    rinv[reg] = 1.0f / __shfl(lf, row, 64);
  }

#pragma unroll
  for (int nb = 0; nb < 4; ++nb)
#pragma unroll
    for (int reg = 0; reg < 16; ++reg) {
      int row = (reg & 3) + 8 * (reg >> 2) + 4 * h;
      size_t qg = rowbase + q0 + w * 32 + row;
      Ctx[qg * HID + hh * HD + nb * 32 + l32] = f2bf(oacc[nb][reg] * rinv[reg]);
    }
}

// ---------------- launch ----------------
extern "C" void kernel_launch(void* const* d_in, const int* in_sizes, int n_in,
                              void* d_out, int out_size, void* d_ws, size_t ws_size,
                              hipStream_t stream) {
  const float* hidden   = (const float*)d_in[0];
  const float* residual = (const float*)d_in[1];
  const float* alibi    = (const float*)d_in[2];
  const float* Wq = (const float*)d_in[3];
  const float* bq = (const float*)d_in[4];
  const float* Wk = (const float*)d_in[5];
  const float* bk = (const float*)d_in[6];
  const float* Wv = (const float*)d_in[7];
  const float* bv = (const float*)d_in[8];
  const float* Wd = (const float*)d_in[9];
  const float* bd = (const float*)d_in[10];
  float* out = (float*)d_out;

  unsigned short* Xb    = (unsigned short*)d_ws;                    // 4096*2048
  unsigned short* Wqkvb = Xb + (size_t)MROWS * HID;                 // 6144*2048
  unsigned short* Wdb   = Wqkvb + (size_t)NQKV * HID;               // 2048*2048
  unsigned short* QKVb  = Wdb + (size_t)HID * HID;                  // 4096*6144
  unsigned short* Ctxb  = QKVb + (size_t)MROWS * NQKV;              // 4096*2048
  unsigned short* VtF   = Ctxb + (size_t)MROWS * HID;               // 32*128*2048 (fused path)

  // fused-Vt path needs 128 MiB of workspace; fall back to separate vtrans otherwise
  const size_t needU = (size_t)MROWS * HID + (size_t)NQKV * HID + (size_t)HID * HID
                     + (size_t)MROWS * NQKV + (size_t)MROWS * HID
                     + (size_t)BATCH * NHEAD * HD * SEQ;
  const bool fused = ws_size >= needU * sizeof(unsigned short);

  const int nTot = (MROWS * HID + 4 * HID * HID) / 4 / 256;   // 24576 blocks, exact
  cvt_all_kernel<<<nTot, 256, 0, stream>>>(hidden, Wq, Wk, Wv, Wd, Xb);

  if (fused) {
    gemm_qkv384_kernel<<<256, 512, 0, stream>>>(Xb, Wqkvb, bq, bk, bv, QKVb, VtF);
    attn_kernel<<<512, 256, 0, stream>>>(QKVb, VtF, alibi, Ctxb);
  } else {
    unsigned short* Vtb = Wqkvb;   // weights dead after gemm_qkv in this path
    gemm_qkv384_kernel<<<256, 512, 0, stream>>>(Xb, Wqkvb, bq, bk, bv, QKVb, nullptr);
    vtrans_kernel<<<dim3(SEQ / 64, HD / 64, BATCH * NHEAD), 256, 0, stream>>>(QKVb, Vtb);
    attn_kernel<<<512, 256, 0, stream>>>(QKVb, Vtb, alibi, Ctxb);
  }
  gemm_out384_kernel<<<256, 512, 0, stream>>>(Ctxb, Wdb, bd, residual, out);
}

// Round 11
// 392.392 us; speedup vs baseline: 1.1317x; 1.0435x over previous
//
#include <hip/hip_runtime.h>

// ---------------- problem constants ----------------
#define HID   2048
#define NHEAD 16
#define HD    128
#define SEQ   2048
#define BATCH 2
#define MROWS (BATCH*SEQ)        // 4096
#define NQKV  (3*HID)            // 6144
#define INV_NORM 0.08838834764831845f
#define LOG2E    1.4426950408889634f
#define SCALE_L2 (INV_NORM*LOG2E)

typedef __attribute__((ext_vector_type(8)))  __bf16 bf16x8;
typedef __attribute__((ext_vector_type(4)))  float  f32x4;
typedef __attribute__((ext_vector_type(16))) float  f32x16;

typedef __attribute__((address_space(1))) void GV;
typedef __attribute__((address_space(3))) void LV;

__device__ __forceinline__ void async16(const void* g, void* l) {
  __builtin_amdgcn_global_load_lds((const GV*)g, (LV*)l, 16, 0, 0);
}

__device__ __forceinline__ unsigned short f2bf(float f) {
  unsigned u = __builtin_bit_cast(unsigned, f);
  u += 0x7FFFu + ((u >> 16) & 1u);       // RNE
  return (unsigned short)(u >> 16);
}

__device__ __forceinline__ unsigned pkbf(float a, float b) {
#if __has_builtin(__builtin_amdgcn_cvt_pk_bf16_f32)
  typedef __attribute__((ext_vector_type(2))) __bf16 bf16x2;
  bf16x2 r = __builtin_amdgcn_cvt_pk_bf16_f32(a, b);
  return __builtin_bit_cast(unsigned, r);
#else
  return (unsigned)f2bf(a) | ((unsigned)f2bf(b) << 16);
#endif
}

// exchange a's upper 32 lanes with b's lower 32 lanes (v_permlane32_swap_b32 a, b)
__device__ __forceinline__ void pl32swap(unsigned &a, unsigned &b) {
#if __has_builtin(__builtin_amdgcn_permlane32_swap)
  typedef __attribute__((ext_vector_type(2))) unsigned u32x2;
  u32x2 r = __builtin_amdgcn_permlane32_swap(a, b, false, false);
  a = r[0]; b = r[1];
#else
  asm volatile("v_permlane32_swap_b32 %0, %1" : "+v"(a), "+v"(b));
#endif
}

__device__ __forceinline__ void mfma16(f32x4& c, bf16x8 a, bf16x8 b) {
  c = __builtin_amdgcn_mfma_f32_16x16x32_bf16(a, b, c, 0, 0, 0);
}

// LDS fragment read with chunk-XOR swizzle (BK=64 -> 8 chunks of 16B per row)
__device__ __forceinline__ bf16x8 frag(const unsigned short* buf, int row, int chunk) {
  return *(const bf16x8*)(buf + ((row * 8 + (chunk ^ (row & 7))) << 3));
}

// ---------------- fp32 -> bf16 cast, flat exact grid (no empty blocks) ----------------
__global__ __launch_bounds__(256) void cvt_all_kernel(
    const float* __restrict__ hidden,
    const float* __restrict__ W0, const float* __restrict__ W1,
    const float* __restrict__ W2, const float* __restrict__ W3,
    unsigned short* __restrict__ Xb) {
  size_t e = ((size_t)blockIdx.x * 256 + threadIdx.x) * 4;
  const float* src;
  if (e < (size_t)MROWS * HID) {
    src = hidden + e;
  } else {
    size_t r = e - (size_t)MROWS * HID;
    int sel = (int)(r >> 22);                 // HID*HID = 2^22
    size_t off = r & ((1u << 22) - 1);
    src = ((sel == 0) ? W0 : (sel == 1) ? W1 : (sel == 2) ? W2 : W3) + off;
  }
  float4 v = *(const float4*)src;
  ushort4 o;
  o.x = f2bf(v.x); o.y = f2bf(v.y); o.z = f2bf(v.z); o.w = f2bf(v.w);
  *(ushort4*)(Xb + e) = o;
}

// ---------------- GEMM 1: QKV projection, persistent 256-block, 3x(256x128) passes ----
// Fused V-transpose epilogue (R10).
#define BUFU (24576)   // ushorts per buffer (48KB): A 16384 + B 8192
#define BUF3 (3 * BUFU)

__global__ __launch_bounds__(512, 2) void gemm_qkv384_kernel(
    const unsigned short* __restrict__ Xb, const unsigned short* __restrict__ Wb,
    const float* __restrict__ bq, const float* __restrict__ bk,
    const float* __restrict__ bv, unsigned short* __restrict__ Cout,
    unsigned short* __restrict__ Vt) {
  __shared__ __align__(16) unsigned short smem[BUF3];   // 144 KiB

  const int tid  = threadIdx.x;
  const int w    = tid >> 6;
  const int lane = tid & 63;
  const int l16  = lane & 15;
  const int quad = lane >> 4;
  const int wm   = (w & 3) * 64;    // 4 M-waves
  const int wn   = (w >> 2) * 64;   // 2 N-waves

  const int wg = blockIdx.x;
  const int sw = (wg & 7) * 32 + (wg >> 3);
  const int m0  = (sw & 15) * 256;
  const int rn0 = (sw >> 4) * 384;

  const int sr  = tid >> 3;
  const int scs = ((tid & 7) ^ (sr & 7)) * 8;
  const unsigned short* aBase = Xb + (size_t)(m0 + sr) * HID + scs;

#define STGA(UB, RB, KT)                                              \
  async16(aBase + (size_t)(RB) * HID + (KT),                          \
          (char*)smem + (UB) * 2 + (RB) * 128 + w * 1024)
#define STGB(UB, RB, KT)                                              \
  async16(bBase + (size_t)(RB) * HID + (KT),                          \
          (char*)smem + (UB) * 2 + 32768 + (RB) * 128 + w * 1024)

#define VM6  asm volatile("s_waitcnt vmcnt(6)" ::: "memory")
#define VM0  asm volatile("s_waitcnt vmcnt(0)" ::: "memory")

#define PHASE(UB, KK, STGBLK, WAITBLK)                                         \
  {                                                                            \
    const unsigned short* Ab = smem + (UB);                                    \
    const unsigned short* Bb = Ab + 16384;                                     \
    bf16x8 ta[4], tb[4];                                                       \
    ta[0] = frag(Ab, wm + l16, (KK) * 4 + quad);                               \
    _Pragma("unroll")                                                          \
    for (int j = 0; j < 4; ++j)  tb[j] = frag(Bb, wn + j * 16 + l16, (KK) * 4 + quad); \
    _Pragma("unroll")                                                          \
    for (int ii = 1; ii < 4; ++ii) ta[ii] = frag(Ab, wm + ii * 16 + l16, (KK) * 4 + quad); \
    STGBLK;                                                                    \
    __builtin_amdgcn_s_setprio(1);                                             \
    _Pragma("unroll")                                                          \
    for (int ii = 0; ii < 4; ++ii)                                             \
      _Pragma("unroll")                                                        \
      for (int j = 0; j < 4; ++j) mfma16(acc[ii][j], ta[ii], tb[j]);           \
    __builtin_amdgcn_s_setprio(0);                                             \
    asm volatile("s_waitcnt lgkmcnt(0)" ::: "memory");                         \
    WAITBLK;                                                                   \
    __builtin_amdgcn_s_barrier();                                              \
  }

  for (int p = 0; p < 3; ++p) {
    const unsigned short* bBase = Wb + (size_t)(rn0 + p * 128 + sr) * HID + scs;

    f32x4 acc[4][4];
    const f32x4 zero = {0.f, 0.f, 0.f, 0.f};
#pragma unroll
    for (int a = 0; a < 4; ++a)
#pragma unroll
      for (int j = 0; j < 4; ++j) acc[a][j] = zero;

    STGA(0, 0, 0);  STGA(0, 64, 0);  STGA(0, 128, 0);  STGA(0, 192, 0);
    STGB(0, 0, 0);  STGB(0, 64, 0);
    STGA(BUFU, 0, 64);  STGA(BUFU, 64, 64);  STGA(BUFU, 128, 64);  STGA(BUFU, 192, 64);
    STGB(BUFU, 0, 64);  STGB(BUFU, 64, 64);
    VM6;
    __builtin_amdgcn_s_barrier();

    int kb = 0;
    for (int g = 0; g < 5; ++g) {
      PHASE(0,        0, { STGA(2*BUFU, 0, kb+128); STGA(2*BUFU, 64, kb+128); STGA(2*BUFU, 128, kb+128); }, {});
      PHASE(0,        1, { STGA(2*BUFU, 192, kb+128); STGB(2*BUFU, 0, kb+128); STGB(2*BUFU, 64, kb+128); }, VM6);
      PHASE(BUFU,     0, { STGA(0, 0, kb+192); STGA(0, 64, kb+192); STGA(0, 128, kb+192); }, {});
      PHASE(BUFU,     1, { STGA(0, 192, kb+192); STGB(0, 0, kb+192); STGB(0, 64, kb+192); }, VM6);
      PHASE(2*BUFU,   0, { STGA(BUFU, 0, kb+256); STGA(BUFU, 64, kb+256); STGA(BUFU, 128, kb+256); }, {});
      PHASE(2*BUFU,   1, { STGA(BUFU, 192, kb+256); STGB(BUFU, 0, kb+256); STGB(BUFU, 64, kb+256); }, VM6);
      PHASE(0,        0, { STGA(2*BUFU, 0, kb+320); STGA(2*BUFU, 64, kb+320); STGA(2*BUFU, 128, kb+320); }, {});
      PHASE(0,        1, { STGA(2*BUFU, 192, kb+320); STGB(2*BUFU, 0, kb+320); STGB(2*BUFU, 64, kb+320); }, VM6);
      PHASE(BUFU,     0, { STGA(0, 0, kb+384); STGA(0, 64, kb+384); STGA(0, 128, kb+384); }, {});
      PHASE(BUFU,     1, { STGA(0, 192, kb+384); STGB(0, 0, kb+384); STGB(0, 64, kb+384); }, VM6);
      PHASE(2*BUFU,   0, { STGA(BUFU, 0, kb+448); STGA(BUFU, 64, kb+448); STGA(BUFU, 128, kb+448); }, {});
      PHASE(2*BUFU,   1, { STGA(BUFU, 192, kb+448); STGB(BUFU, 0, kb+448); STGB(BUFU, 64, kb+448); }, VM6);
      kb += 384;
    }

    PHASE(0,    0, {}, {});
    PHASE(0,    1, {}, VM0);
    PHASE(BUFU, 0, {}, {});
    PHASE(BUFU, 1, {}, {});

#pragma unroll
    for (int j = 0; j < 4; ++j) {
      int ng = rn0 + p * 128 + wn + j * 16 + l16;
      float bias = (ng < HID) ? bq[ng] : (ng < 2 * HID ? bk[ng - HID] : bv[ng - 2 * HID]);
      if (Vt != nullptr && ng >= 2 * HID) {
        const int vidx = ng - 2 * HID;
        const int bb = m0 >> 11;
        unsigned short* vrow = Vt
            + ((size_t)((bb * 16 + (vidx >> 7)) * 128 + (vidx & 127))) * SEQ
            + (m0 & 2047) + wm + quad * 4;
#pragma unroll
        for (int a = 0; a < 4; ++a) {
          ushort4 pk4;
          pk4.x = f2bf(acc[a][j][0] + bias);
          pk4.y = f2bf(acc[a][j][1] + bias);
          pk4.z = f2bf(acc[a][j][2] + bias);
          pk4.w = f2bf(acc[a][j][3] + bias);
          *(ushort4*)(vrow + a * 16) = pk4;
        }
      } else {
#pragma unroll
        for (int a = 0; a < 4; ++a)
#pragma unroll
          for (int r = 0; r < 4; ++r) {
            int mg = m0 + wm + a * 16 + quad * 4 + r;
            Cout[(size_t)mg * NQKV + ng] = f2bf(acc[a][j][r] + bias);
          }
      }
    }
  }
#undef STGA
#undef STGB
#undef PHASE
#undef VM6
#undef VM0
}

// ---------------- GEMM 2: out-proj, SAME persistent structure (single pass) ----------------
__global__ __launch_bounds__(512, 2) void gemm_out384_kernel(
    const unsigned short* __restrict__ Ctx, const unsigned short* __restrict__ Wdb,
    const float* __restrict__ bd, const float* __restrict__ Res,
    float* __restrict__ Out) {
  __shared__ __align__(16) unsigned short smem[BUF3];   // 144 KiB

  const int tid  = threadIdx.x;
  const int w    = tid >> 6;
  const int lane = tid & 63;
  const int l16  = lane & 15;
  const int quad = lane >> 4;
  const int wm   = (w & 3) * 64;
  const int wn   = (w >> 2) * 64;

  const int wg = blockIdx.x;
  const int sw = (wg & 7) * 32 + (wg >> 3);
  const int m0  = (sw & 15) * 256;
  const int rn0 = (sw >> 4) * 128;

  const int sr  = tid >> 3;
  const int scs = ((tid & 7) ^ (sr & 7)) * 8;
  const unsigned short* aBase = Ctx + (size_t)(m0 + sr) * HID + scs;
  const unsigned short* bBase = Wdb + (size_t)(rn0 + sr) * HID + scs;

#define STGA(UB, RB, KT)                                              \
  async16(aBase + (size_t)(RB) * HID + (KT),                          \
          (char*)smem + (UB) * 2 + (RB) * 128 + w * 1024)
#define STGB(UB, RB, KT)                                              \
  async16(bBase + (size_t)(RB) * HID + (KT),                          \
          (char*)smem + (UB) * 2 + 32768 + (RB) * 128 + w * 1024)

#define VM6  asm volatile("s_waitcnt vmcnt(6)" ::: "memory")
#define VM0  asm volatile("s_waitcnt vmcnt(0)" ::: "memory")

#define PHASE(UB, KK, STGBLK, WAITBLK)                                         \
  {                                                                            \
    const unsigned short* Ab = smem + (UB);                                    \
    const unsigned short* Bb = Ab + 16384;                                     \
    bf16x8 ta[4], tb[4];                                                       \
    ta[0] = frag(Ab, wm + l16, (KK) * 4 + quad);                               \
    _Pragma("unroll")                                                          \
    for (int j = 0; j < 4; ++j)  tb[j] = frag(Bb, wn + j * 16 + l16, (KK) * 4 + quad); \
    _Pragma("unroll")                                                          \
    for (int ii = 1; ii < 4; ++ii) ta[ii] = frag(Ab, wm + ii * 16 + l16, (KK) * 4 + quad); \
    STGBLK;                                                                    \
    __builtin_amdgcn_s_setprio(1);                                             \
    _Pragma("unroll")                                                          \
    for (int ii = 0; ii < 4; ++ii)                                             \
      _Pragma("unroll")                                                        \
      for (int j = 0; j < 4; ++j) mfma16(acc[ii][j], ta[ii], tb[j]);           \
    __builtin_amdgcn_s_setprio(0);                                             \
    asm volatile("s_waitcnt lgkmcnt(0)" ::: "memory");                         \
    WAITBLK;                                                                   \
    __builtin_amdgcn_s_barrier();                                              \
  }

  f32x4 acc[4][4];
  const f32x4 zero = {0.f, 0.f, 0.f, 0.f};
#pragma unroll
  for (int a = 0; a < 4; ++a)
#pragma unroll
    for (int j = 0; j < 4; ++j) acc[a][j] = zero;

  STGA(0, 0, 0);  STGA(0, 64, 0);  STGA(0, 128, 0);  STGA(0, 192, 0);
  STGB(0, 0, 0);  STGB(0, 64, 0);
  STGA(BUFU, 0, 64);  STGA(BUFU, 64, 64);  STGA(BUFU, 128, 64);  STGA(BUFU, 192, 64);
  STGB(BUFU, 0, 64);  STGB(BUFU, 64, 64);
  VM6;
  __builtin_amdgcn_s_barrier();

  int kb = 0;
  for (int g = 0; g < 5; ++g) {
    PHASE(0,        0, { STGA(2*BUFU, 0, kb+128); STGA(2*BUFU, 64, kb+128); STGA(2*BUFU, 128, kb+128); }, {});
    PHASE(0,        1, { STGA(2*BUFU, 192, kb+128); STGB(2*BUFU, 0, kb+128); STGB(2*BUFU, 64, kb+128); }, VM6);
    PHASE(BUFU,     0, { STGA(0, 0, kb+192); STGA(0, 64, kb+192); STGA(0, 128, kb+192); }, {});
    PHASE(BUFU,     1, { STGA(0, 192, kb+192); STGB(0, 0, kb+192); STGB(0, 64, kb+192); }, VM6);
    PHASE(2*BUFU,   0, { STGA(BUFU, 0, kb+256); STGA(BUFU, 64, kb+256); STGA(BUFU, 128, kb+256); }, {});
    PHASE(2*BUFU,   1, { STGA(BUFU, 192, kb+256); STGB(BUFU, 0, kb+256); STGB(BUFU, 64, kb+256); }, VM6);
    PHASE(0,        0, { STGA(2*BUFU, 0, kb+320); STGA(2*BUFU, 64, kb+320); STGA(2*BUFU, 128, kb+320); }, {});
    PHASE(0,        1, { STGA(2*BUFU, 192, kb+320); STGB(2*BUFU, 0, kb+320); STGB(2*BUFU, 64, kb+320); }, VM6);
    PHASE(BUFU,     0, { STGA(0, 0, kb+384); STGA(0, 64, kb+384); STGA(0, 128, kb+384); }, {});
    PHASE(BUFU,     1, { STGA(0, 192, kb+384); STGB(0, 0, kb+384); STGB(0, 64, kb+384); }, VM6);
    PHASE(2*BUFU,   0, { STGA(BUFU, 0, kb+448); STGA(BUFU, 64, kb+448); STGA(BUFU, 128, kb+448); }, {});
    PHASE(2*BUFU,   1, { STGA(BUFU, 192, kb+448); STGB(BUFU, 0, kb+448); STGB(BUFU, 64, kb+448); }, VM6);
    kb += 384;
  }

  PHASE(0,    0, {}, {});
  PHASE(0,    1, {}, VM0);
  PHASE(BUFU, 0, {}, {});
  PHASE(BUFU, 1, {}, {});

#pragma unroll
  for (int j = 0; j < 4; ++j) {
    int ng = rn0 + wn + j * 16 + l16;
    float bias = bd[ng];
#pragma unroll
    for (int a = 0; a < 4; ++a)
#pragma unroll
      for (int r = 0; r < 4; ++r) {
        int mg = m0 + wm + a * 16 + quad * 4 + r;
        size_t off = (size_t)mg * HID + ng;
        Out[off] = acc[a][j][r] + bias + Res[off];
      }
  }
#undef STGA
#undef STGB
#undef PHASE
#undef VM6
#undef VM0
}

// ---------------- V transpose (FALLBACK only, when ws too small for fused Vt) ----------------
__global__ __launch_bounds__(256) void vtrans_kernel(const unsigned short* __restrict__ QKV,
                                                     unsigned short* __restrict__ Vt) {
  __shared__ __align__(16) unsigned short T[64][72];
  const int s0 = blockIdx.x * 64, d0 = blockIdx.y * 64, bh = blockIdx.z;
  const int b = bh >> 4, h = bh & 15;
  const int tid = threadIdx.x;
#pragma unroll
  for (int i = 0; i < 2; ++i) {
    int idx = i * 256 + tid;
    int r = idx >> 3, ch = idx & 7;
    const unsigned short* g = QKV + ((size_t)b * SEQ + s0 + r) * NQKV + 2 * HID + h * HD + d0 + ch * 8;
    *(uint4*)(&T[r][ch * 8]) = *(const uint4*)g;
  }
  __syncthreads();
#pragma unroll
  for (int i = 0; i < 2; ++i) {
    int idx = i * 256 + tid;
    int d = idx >> 3, ch = idx & 7;
    unsigned short v[8];
#pragma unroll
    for (int x = 0; x < 8; ++x) v[x] = T[ch * 8 + x][d];
    unsigned short* g = Vt + ((size_t)bh * HD + d0 + d) * SEQ + s0 + ch * 8;
    *(uint4*)g = *(const uint4*)v;
  }
}

// ---------------- flash attention: 8-wave block, shared K/V staging (m214-style) ----------------
// Grid 256 (XCD-pinned: bid = (bh&7) + 8*(qb + 8*(bh>>3))); block = 512 thr = 8 waves,
// each wave owns 32 q-rows (256 q-rows/block). K/V staged ONCE per 256 q-rows (was per
// 128) -> staging instrs and K/V refetch halve. LDS: Ks0/Ks1/Vts0/Vts1 16K + Als 8K =
// 72KB. T15 pipeline retained; vmcnt counts re-derived for 2-load stages:
// prologue vmcnt(4); steady vmcnt(4) (drains the tile needed this iter, >=1 iter old);
// tail vmcnt(2) -> vmcnt(0). One barrier per iter.
__global__ __launch_bounds__(512, 2) void attn_kernel(
    const unsigned short* __restrict__ QKV, const unsigned short* __restrict__ Vt,
    const float* __restrict__ alibi, unsigned short* __restrict__ Ctx) {
  __shared__ __align__(16) char smem[73728];
  unsigned short* Ks0  = (unsigned short*)smem;
  unsigned short* Ks1  = (unsigned short*)(smem + 16384);
  unsigned short* Vts0 = (unsigned short*)(smem + 32768);
  unsigned short* Vts1 = (unsigned short*)(smem + 49152);
  float*          Alsf = (float*)(smem + 65536);
  unsigned short* Qs   = (unsigned short*)smem;   // alias: Q staging (64 KB over all 4 bufs)

  const int tid = threadIdx.x, w = tid >> 6, lane = tid & 63;
  const int l32 = lane & 31, h = lane >> 5;
  // XCD-pinned decode: all 8 q-blocks of one bh share an XCD
  const int bid = blockIdx.x;
  const int t  = bid >> 3;
  const int q0 = (t & 7) * 256;
  const int bh = (bid & 7) + 8 * (t >> 3);
  const int b = bh >> 4, hh = bh & 15;
  const size_t rowbase = (size_t)b * SEQ;
  const float* ali = alibi + (size_t)bh * SEQ;
  const unsigned short* Vbh = Vt + (size_t)bh * HD * SEQ;

  // ---- stage Q (256x128, aliases all K/V bufs) + alibi row (8KB) ----
  {
    const unsigned short* qbase = QKV + (rowbase + q0) * NQKV + hh * HD;
#pragma unroll
    for (int i = 0; i < 8; ++i) {
      int slot = i * 512 + w * 64 + lane;              // 0..4095
      int r = slot >> 4, c = (slot & 15) ^ (r & 15);
      async16(qbase + (size_t)r * NQKV + c * 8, (char*)Qs + (size_t)(i * 512 + w * 64) * 16);
    }
    // alibi: 2048 f32 = 512 x 16B, one per thread
    async16((const char*)ali + (size_t)(w * 64 + lane) * 16, (char*)Alsf + (size_t)(w * 64) * 16);
  }
  __syncthreads();
  bf16x8 qf[8];
  {
    int qr = w * 32 + l32;                             // 0..255
#pragma unroll
    for (int ks = 0; ks < 8; ++ks) {
      int c = (ks * 2 + h) ^ (qr & 15);
      qf[ks] = *(const bf16x8*)(Qs + (qr * 16 + c) * 8);
    }
  }

  f32x16 oacc[4];
  float l_acc = 0.f;
#pragma unroll
  for (int nb = 0; nb < 4; ++nb)
#pragma unroll
    for (int r = 0; r < 16; ++r) oacc[nb][r] = 0.f;

  __syncthreads();   // qf reads complete before K staging overwrites alias

// stage K(T)->KD: 64x128 = 16KB = 1024 slots; 512 thr -> 2 async16 each
#define STAGE_K(T, KD)                                                           \
  {                                                                              \
    const unsigned short* kbase = QKV + (rowbase + (size_t)(T) * 64) * NQKV + HID + hh * HD; \
    _Pragma("unroll")                                                            \
    for (int i = 0; i < 2; ++i) {                                                \
      int slot = i * 512 + w * 64 + lane;                                        \
      int r = slot >> 4, c = (slot & 15) ^ (r & 15);                             \
      async16(kbase + (size_t)r * NQKV + c * 8, (char*)(KD) + (size_t)(i * 512 + w * 64) * 16); \
    }                                                                            \
  }
#define STAGE_V(T, VD)                                                           \
  {                                                                              \
    const unsigned short* vbase = Vbh + (T) * 64;                                \
    _Pragma("unroll")                                                            \
    for (int i = 0; i < 2; ++i) {                                                \
      int slot = i * 512 + w * 64 + lane;                                        \
      int r = slot >> 3, c = (slot & 7) ^ (r & 7);                               \
      async16(vbase + (size_t)r * SEQ + c * 8, (char*)(VD) + (size_t)(i * 512 + w * 64) * 16); \
    }                                                                            \
  }

#define QKT(SACC, KBUF)                                                          \
  {                                                                              \
    _Pragma("unroll")                                                            \
    for (int mb = 0; mb < 2; ++mb)                                               \
      _Pragma("unroll")                                                          \
      for (int r = 0; r < 16; ++r) (SACC)[mb][r] = 0.f;                          \
    __builtin_amdgcn_s_setprio(1);                                               \
    _Pragma("unroll")                                                            \
    for (int ks = 0; ks < 8; ++ks)                                               \
      _Pragma("unroll")                                                          \
      for (int mb = 0; mb < 2; ++mb) {                                           \
        bf16x8 kf = *(const bf16x8*)((KBUF) + ((mb * 32 + l32) * 16 + ((ks * 2 + h) ^ (l32 & 15))) * 8); \
        (SACC)[mb] = __builtin_amdgcn_mfma_f32_32x32x16_bf16(kf, qf[ks], (SACC)[mb], 0, 0, 0); \
      }                                                                          \
    __builtin_amdgcn_s_setprio(0);                                               \
  }

#define SOFTMAX(SACC, KT, PFR)                                                   \
  {                                                                              \
    const float* alsk = Alsf + (KT) * 64 + 4 * h;                                \
    _Pragma("unroll")                                                            \
    for (int mb = 0; mb < 2; ++mb) {                                             \
      float p[16];                                                               \
      _Pragma("unroll")                                                          \
      for (int g = 0; g < 4; ++g) {                                              \
        float4 av = *(const float4*)(alsk + mb * 32 + g * 8);                    \
        p[g * 4 + 0] = __builtin_amdgcn_exp2f((SACC)[mb][g * 4 + 0] * SCALE_L2 + av.x * LOG2E); \
        p[g * 4 + 1] = __builtin_amdgcn_exp2f((SACC)[mb][g * 4 + 1] * SCALE_L2 + av.y * LOG2E); \
        p[g * 4 + 2] = __builtin_amdgcn_exp2f((SACC)[mb][g * 4 + 2] * SCALE_L2 + av.z * LOG2E); \
        p[g * 4 + 3] = __builtin_amdgcn_exp2f((SACC)[mb][g * 4 + 3] * SCALE_L2 + av.w * LOG2E); \
        l_acc += (p[g * 4 + 0] + p[g * 4 + 1]) + (p[g * 4 + 2] + p[g * 4 + 3]);  \
      }                                                                          \
      unsigned c0 = pkbf(p[0],  p[1]),  c1 = pkbf(p[2],  p[3]);                  \
      unsigned c2 = pkbf(p[4],  p[5]),  c3 = pkbf(p[6],  p[7]);                  \
      unsigned c4 = pkbf(p[8],  p[9]),  c5 = pkbf(p[10], p[11]);                 \
      unsigned c6 = pkbf(p[12], p[13]), c7 = pkbf(p[14], p[15]);                 \
      pl32swap(c0, c2);  pl32swap(c1, c3);                                       \
      pl32swap(c4, c6);  pl32swap(c5, c7);                                       \
      uint4 f0; f0.x = c0; f0.y = c1; f0.z = c2; f0.w = c3;                      \
      uint4 f1; f1.x = c4; f1.y = c5; f1.z = c6; f1.w = c7;                      \
      (PFR)[mb * 2 + 0] = __builtin_bit_cast(bf16x8, f0);                        \
      (PFR)[mb * 2 + 1] = __builtin_bit_cast(bf16x8, f1);                        \
    }                                                                            \
  }

#define PVOP(PFR, VBUF)                                                          \
  {                                                                              \
    __builtin_amdgcn_s_setprio(1);                                               \
    _Pragma("unroll")                                                            \
    for (int ks2 = 0; ks2 < 4; ++ks2) {                                          \
      bf16x8 pf = (PFR)[ks2];                                                    \
      _Pragma("unroll")                                                          \
      for (int nb = 0; nb < 4; ++nb) {                                           \
        bf16x8 vf = *(const bf16x8*)((VBUF) + ((nb * 32 + l32) * 8 + ((ks2 * 2 + h) ^ (l32 & 7))) * 8); \
        oacc[nb] = __builtin_amdgcn_mfma_f32_32x32x16_bf16(pf, vf, oacc[nb], 0, 0, 0); \
      }                                                                          \
    }                                                                            \
    __builtin_amdgcn_s_setprio(0);                                               \
  }

  // prologue: tiles 0,1 (2 loads per stage); drain tile 0 (vmcnt(4) leaves K1,V1)
  STAGE_K(0, Ks0);  STAGE_V(0, Vts0);
  STAGE_K(1, Ks1);  STAGE_V(1, Vts1);
  asm volatile("s_waitcnt vmcnt(4)" ::: "memory");
  __builtin_amdgcn_s_barrier();

  f32x16 sA[2], sB[2];
  QKT(sA, Ks0);
  asm volatile("s_waitcnt lgkmcnt(0)" ::: "memory");
  __builtin_amdgcn_s_barrier();   // all waves' tile-0 K reads retired -> Ks0 stageable

  for (int kt = 0; kt < 30; kt += 2) {
    // even: cur tile kt (bufs 0), next tile kt+1 (bufs 1)
    STAGE_K(kt + 2, Ks0);
    asm volatile("s_waitcnt vmcnt(4)" ::: "memory");   // K(kt+1) landed; V(kt) older
    QKT(sB, Ks1);
    { bf16x8 pfr[4]; SOFTMAX(sA, kt, pfr); PVOP(pfr, Vts0); }
    asm volatile("s_waitcnt lgkmcnt(0)" ::: "memory");
    __builtin_amdgcn_s_barrier();
    STAGE_V(kt + 2, Vts0);
    // odd: cur tile kt+1 (bufs 1), next tile kt+2 (bufs 0)
    STAGE_K(kt + 3, Ks1);
    asm volatile("s_waitcnt vmcnt(4)" ::: "memory");   // V(kt+1), K(kt+2) landed
    QKT(sA, Ks0);
    { bf16x8 pfr[4]; SOFTMAX(sB, kt + 1, pfr); PVOP(pfr, Vts1); }
    asm volatile("s_waitcnt lgkmcnt(0)" ::: "memory");
    __builtin_amdgcn_s_barrier();
    STAGE_V(kt + 3, Vts1);
  }

  // kt = 30: outstanding [V30, K31, V31]
  asm volatile("s_waitcnt vmcnt(2)" ::: "memory");     // V30, K31 landed
  QKT(sB, Ks1);
  { bf16x8 pfr[4]; SOFTMAX(sA, 30, pfr); PVOP(pfr, Vts0); }
  asm volatile("s_waitcnt lgkmcnt(0) vmcnt(0)" ::: "memory");   // V31 landed
  __builtin_amdgcn_s_barrier();
  // kt = 31
  { bf16x8 pfr[4]; SOFTMAX(sB, 31, pfr); PVOP(pfr, Vts1); }
  asm volatile("s_waitcnt lgkmcnt(0)" ::: "memory");

#undef STAGE_K
#undef STAGE_V
#undef QKT
#undef SOFTMAX
#undef PVOP

  float lf = l_acc + __shfl_xor(l_acc, 32, 64);
  float rinv[16];
#pragma unroll
  for (int reg = 0; reg < 16; ++reg) {
    int row = (reg & 3) + 8 * (reg >> 2) + 4 * h;
    rinv[reg] = 1.0f / __shfl(lf, row, 64);
  }

#pragma unroll
  for (int nb = 0; nb < 4; ++nb)
#pragma unroll
    for (int reg = 0; reg < 16; ++reg) {
      int row = (reg & 3) + 8 * (reg >> 2) + 4 * h;
      size_t qg = rowbase + q0 + w * 32 + row;
      Ctx[qg * HID + hh * HD + nb * 32 + l32] = f2bf(oacc[nb][reg] * rinv[reg]);
    }
}

// ---------------- launch ----------------
extern "C" void kernel_launch(void* const* d_in, const int* in_sizes, int n_in,
                              void* d_out, int out_size, void* d_ws, size_t ws_size,
                              hipStream_t stream) {
  const float* hidden   = (const float*)d_in[0];
  const float* residual = (const float*)d_in[1];
  const float* alibi    = (const float*)d_in[2];
  const float* Wq = (const float*)d_in[3];
  const float* bq = (const float*)d_in[4];
  const float* Wk = (const float*)d_in[5];
  const float* bk = (const float*)d_in[6];
  const float* Wv = (const float*)d_in[7];
  const float* bv = (const float*)d_in[8];
  const float* Wd = (const float*)d_in[9];
  const float* bd = (const float*)d_in[10];
  float* out = (float*)d_out;

  unsigned short* Xb    = (unsigned short*)d_ws;                    // 4096*2048
  unsigned short* Wqkvb = Xb + (size_t)MROWS * HID;                 // 6144*2048
  unsigned short* Wdb   = Wqkvb + (size_t)NQKV * HID;               // 2048*2048
  unsigned short* QKVb  = Wdb + (size_t)HID * HID;                  // 4096*6144
  unsigned short* Ctxb  = QKVb + (size_t)MROWS * NQKV;              // 4096*2048
  unsigned short* VtF   = Ctxb + (size_t)MROWS * HID;               // 32*128*2048 (fused path)

  const size_t needU = (size_t)MROWS * HID + (size_t)NQKV * HID + (size_t)HID * HID
                     + (size_t)MROWS * NQKV + (size_t)MROWS * HID
                     + (size_t)BATCH * NHEAD * HD * SEQ;
  const bool fused = ws_size >= needU * sizeof(unsigned short);

  const int nTot = (MROWS * HID + 4 * HID * HID) / 4 / 256;   // 24576 blocks, exact
  cvt_all_kernel<<<nTot, 256, 0, stream>>>(hidden, Wq, Wk, Wv, Wd, Xb);

  if (fused) {
    gemm_qkv384_kernel<<<256, 512, 0, stream>>>(Xb, Wqkvb, bq, bk, bv, QKVb, VtF);
    attn_kernel<<<256, 512, 0, stream>>>(QKVb, VtF, alibi, Ctxb);
  } else {
    unsigned short* Vtb = Wqkvb;   // weights dead after gemm_qkv in this path
    gemm_qkv384_kernel<<<256, 512, 0, stream>>>(Xb, Wqkvb, bq, bk, bv, QKVb, nullptr);
    vtrans_kernel<<<dim3(SEQ / 64, HD / 64, BATCH * NHEAD), 256, 0, stream>>>(QKVb, Vtb);
    attn_kernel<<<256, 512, 0, stream>>>(QKVb, Vtb, alibi, Ctxb);
  }
  gemm_out384_kernel<<<256, 512, 0, stream>>>(Ctxb, Wdb, bd, residual, out);
}